// Round 6
// baseline (19287.379 us; speedup 1.0000x reference)
//
#include <hip/hip_runtime.h>
#include <cmath>
#include <type_traits>

#define NL 16
#define TBL_N (1u << 19)
#define HID 64

typedef float f4v __attribute__((ext_vector_type(4)));
typedef float f2v __attribute__((ext_vector_type(2)));

struct Res16 { float r[NL]; };

__device__ __forceinline__ unsigned short f2bf(float f) {
    unsigned u = __float_as_uint(f);
    unsigned r = (u + 0x7FFFu + ((u >> 16) & 1u)) >> 16;   // RNE
    return (unsigned short)r;
}
__device__ __forceinline__ unsigned pack_bf(float a, float b) {
    return (unsigned)f2bf(a) | ((unsigned)f2bf(b) << 16);
}
__device__ __forceinline__ void corner_vals(unsigned v, float& f0, float& f1) {
    f0 = __uint_as_float(v << 16);
    f1 = __uint_as_float(v & 0xffff0000u);
}
__device__ __forceinline__ void corner_vals(float2 v, float& f0, float& f1) {
    f0 = v.x; f1 = v.y;
}

__global__ __launch_bounds__(256) void repack_bf16(const float* __restrict__ src,
                                                   unsigned* __restrict__ dst, int n) {
    int i = blockIdx.x * blockDim.x + threadIdx.x;
    if (i >= n) return;
    f2v v = __builtin_nontemporal_load((const f2v*)src + i);
    dst[i] = pack_bf(v.x, v.y);
}

// ======================= Kernel E: hash-grid encode ========================
// NT on all streaming accesses: keep L2/L3 for the hash table only.
__global__ __launch_bounds__(256) void nerf_encode(
    const float* __restrict__ x,
    const unsigned* __restrict__ tbl,
    unsigned* __restrict__ enc,
    Res16 rt, int p0, int P, int n_pts)
{
    int p = blockIdx.x * blockDim.x + threadIdx.x;
    if (p >= P) return;
    int n = p0 + p;
    if (n >= n_pts) return;

    float px = (__builtin_nontemporal_load(&x[3*n+0]) + 1.f) * 0.5f;
    float py = (__builtin_nontemporal_load(&x[3*n+1]) + 1.f) * 0.5f;
    float pz = (__builtin_nontemporal_load(&x[3*n+2]) + 1.f) * 0.5f;

    #pragma unroll 4
    for (int l = 0; l < NL; l++) {
        float res = rt.r[l];
        float xs = px*res, ys = py*res, zs = pz*res;
        float fx = floorf(xs), fy = floorf(ys), fz = floorf(zs);
        float wx = xs - fx, wy = ys - fy, wz = zs - fz;
        float ax = 1.f - wx, ay = 1.f - wy, az = 1.f - wz;
        unsigned X = (unsigned)fx, Y = (unsigned)fy, Z = (unsigned)fz;
        unsigned hx0 = X,               hx1 = X + 1u;
        unsigned hy0 = Y * 2654435761u, hy1 = hy0 + 2654435761u;
        unsigned hz0 = Z * 805459861u,  hz1 = hz0 + 805459861u;
        const unsigned* base = tbl + (size_t)l * TBL_N;

        float e0 = 0.f, e1 = 0.f;
        #pragma unroll
        for (int c = 0; c < 8; c++) {
            unsigned idx = (((c & 4) ? hx1 : hx0) ^
                            ((c & 2) ? hy1 : hy0) ^
                            ((c & 1) ? hz1 : hz0)) & (TBL_N - 1u);
            unsigned v = base[idx];
            float f0, f1;
            corner_vals(v, f0, f1);
            float wgt = ((c & 4) ? wx : ax) * ((c & 2) ? wy : ay) * ((c & 1) ? wz : az);
            e0 += wgt * f0;
            e1 += wgt * f1;
        }
        __builtin_nontemporal_store(pack_bf(e0, e1), &enc[(size_t)l * P + p]);
    }
}

// ======================= Kernel M: LDS weights, 2 pts/thread ===============
#define SW0_O 0
#define SB0_O 2048
#define SW1_O 2112
#define SB1_O 3136
#define CW0_O 3152
#define CB0_O 8208
#define CW1_O 8272
#define CB1_O 12368
#define CW2_O 12432
#define CB2_O 12624
#define WTOT  12628

__global__ __launch_bounds__(256) void nerf_mlp(
    const unsigned* __restrict__ enc,
    const float* __restrict__ dvec,
    const int*   __restrict__ app_idx,
    const float* __restrict__ app_table,
    const float* __restrict__ sw0, const float* __restrict__ sb0,
    const float* __restrict__ sw1, const float* __restrict__ sb1,
    const float* __restrict__ cw0, const float* __restrict__ cb0,
    const float* __restrict__ cw1, const float* __restrict__ cb1,
    const float* __restrict__ cw2, const float* __restrict__ cb2,
    float* __restrict__ out, int p0, int P, int n_pts)
{
    __shared__ __align__(16) float W[WTOT];
    int tid = threadIdx.x;
    for (int i = tid; i < 2048; i += 256) W[SW0_O+i] = sw0[i];
    for (int i = tid; i < 64;   i += 256) W[SB0_O+i] = sb0[i];
    for (int i = tid; i < 1024; i += 256) W[SW1_O+i] = sw1[i];
    if (tid < 16) W[SB1_O+tid] = sb1[tid];
    for (int i = tid; i < 5056; i += 256) W[CW0_O+i] = cw0[i];
    for (int i = tid; i < 64;   i += 256) W[CB0_O+i] = cb0[i];
    for (int i = tid; i < 4096; i += 256) W[CW1_O+i] = cw1[i];
    for (int i = tid; i < 64;   i += 256) W[CB1_O+i] = cb1[i];
    for (int i = tid; i < 192;  i += 256) W[CW2_O+i] = cw2[i];
    if (tid < 3) W[CB2_O+tid] = cb2[tid];
    __syncthreads();

    int pL = blockIdx.x * 512 + tid;          // point A (local)
    int pA = pL, pB = pL + 256;
    bool vA = pA < P, vB = pB < P;
    int pAc = vA ? pA : 0;
    int pBc = vB ? pB : 0;
    int nA = p0 + pAc, nB = p0 + pBc;
    if (!vA && !vB) return;

    // ---- density layer 0 ----
    float h[2][HID];
    #pragma unroll
    for (int o = 0; o < HID; o++) { float b = W[SB0_O+o]; h[0][o] = b; h[1][o] = b; }
    const unsigned* epA = enc + pAc;
    const unsigned* epB = enc + pBc;
    #pragma unroll
    for (int l = 0; l < NL; l++) {
        unsigned uA = __builtin_nontemporal_load(epA + (size_t)l * P);
        unsigned uB = __builtin_nontemporal_load(epB + (size_t)l * P);
        float eA0, eA1, eB0, eB1;
        corner_vals(uA, eA0, eA1);
        corner_vals(uB, eB0, eB1);
        const float* r0 = &W[SW0_O + 2*l*HID];
        #pragma unroll
        for (int o = 0; o < HID; o++) {
            float w0 = r0[o], w1 = r0[HID+o];
            h[0][o] += eA0*w0 + eA1*w1;
            h[1][o] += eB0*w0 + eB1*w1;
        }
    }
    #pragma unroll
    for (int o = 0; o < HID; o++) { h[0][o] = fmaxf(h[0][o], 0.f); h[1][o] = fmaxf(h[1][o], 0.f); }

    // ---- density layer 1 ----
    float h1[2][16];
    #pragma unroll
    for (int o = 0; o < 16; o++) { float b = W[SB1_O+o]; h1[0][o] = b; h1[1][o] = b; }
    #pragma unroll
    for (int i = 0; i < HID; i++) {
        const float* wr = &W[SW1_O + i*16];
        float a = h[0][i], bq = h[1][i];
        #pragma unroll
        for (int o = 0; o < 16; o++) { float w = wr[o]; h1[0][o] += a*w; h1[1][o] += bq*w; }
    }

    float sg[2];
    #pragma unroll
    for (int q = 0; q < 2; q++) {
        float z100 = 100.f * h1[q][0];
        sg[q] = (z100 > 20.f) ? h1[q][0] : (log1pf(expf(z100)) * 0.01f);
    }

    // ---- color layer 0: geo rows first ----
    float c1[2][HID];
    #pragma unroll
    for (int o = 0; o < HID; o++) { float b = W[CB0_O+o]; c1[0][o] = b; c1[1][o] = b; }
    #pragma unroll
    for (int i = 0; i < 15; i++) {
        const float* wr = &W[CW0_O + i*HID];
        float a = h1[0][i+1], bq = h1[1][i+1];
        #pragma unroll
        for (int o = 0; o < HID; o++) { float w = wr[o]; c1[0][o] += a*w; c1[1][o] += bq*w; }
    }

    // ---- SH rows ----
    {
        float shv[2][16];
        #pragma unroll
        for (int q = 0; q < 2; q++) {
            int n = q ? nB : nA;
            float dx = __builtin_nontemporal_load(&dvec[3*n+0]);
            float dy = __builtin_nontemporal_load(&dvec[3*n+1]);
            float dz = __builtin_nontemporal_load(&dvec[3*n+2]);
            float invn = 1.0f / sqrtf(dx*dx + dy*dy + dz*dz);
            dx *= invn; dy *= invn; dz *= invn;
            float xx = dx*dx, yy = dy*dy, zz = dz*dz;
            float xy = dx*dy, yz = dy*dz, xz = dx*dz;
            shv[q][0]  = 0.28209479177387814f;
            shv[q][1]  = -0.48860251190291987f * dy;
            shv[q][2]  =  0.48860251190291987f * dz;
            shv[q][3]  = -0.48860251190291987f * dx;
            shv[q][4]  =  1.0925484305920792f * xy;
            shv[q][5]  = -1.0925484305920792f * yz;
            shv[q][6]  =  0.94617469575756f * zz - 0.31539156525252005f;
            shv[q][7]  = -1.0925484305920792f * xz;
            shv[q][8]  =  0.5462742152960396f * (xx - yy);
            shv[q][9]  = -0.5900435899266435f * dy * (3.f * xx - yy);
            shv[q][10] =  2.890611442640554f * xy * dz;
            shv[q][11] = -0.4570457994644657f * dy * (4.f * zz - xx - yy);
            shv[q][12] =  0.37317633259011546f * dz * (2.f * zz - 3.f * xx - 3.f * yy);
            shv[q][13] = -0.4570457994644657f * dx * (4.f * zz - xx - yy);
            shv[q][14] =  1.445305721320277f * dz * (xx - yy);
            shv[q][15] = -0.5900435899266435f * dx * (xx - 3.f * yy);
        }
        #pragma unroll
        for (int i = 0; i < 16; i++) {
            const float* wr = &W[CW0_O + (15+i)*HID];
            float a = shv[0][i], bq = shv[1][i];
            #pragma unroll
            for (int o = 0; o < HID; o++) { float w = wr[o]; c1[0][o] += a*w; c1[1][o] += bq*w; }
        }
    }

    // ---- app rows ----
    {
        int aiA = __builtin_nontemporal_load(&app_idx[nA]);
        int aiB = __builtin_nontemporal_load(&app_idx[nB]);
        const f4v* rowA = (const f4v*)(app_table + (size_t)aiA * 48);
        const f4v* rowB = (const f4v*)(app_table + (size_t)aiB * 48);
        for (int j4 = 0; j4 < 12; j4++) {            // rolled
            f4v a4 = rowA[j4];
            f4v b4 = rowB[j4];
            const float* wr = &W[CW0_O + (31 + 4*j4)*HID];
            #pragma unroll
            for (int k = 0; k < 4; k++) {
                float a = a4[k], bq = b4[k];
                const float* wk = wr + k*HID;
                #pragma unroll
                for (int o = 0; o < HID; o++) { float w = wk[o]; c1[0][o] += a*w; c1[1][o] += bq*w; }
            }
        }
    }
    #pragma unroll
    for (int o = 0; o < HID; o++) { c1[0][o] = fmaxf(c1[0][o], 0.f); c1[1][o] = fmaxf(c1[1][o], 0.f); }

    // ---- color layers 1+2, in 32-wide halves to bound VGPR ----
    float rgb[2][3];
    #pragma unroll
    for (int j = 0; j < 3; j++) { float b = W[CB2_O+j]; rgb[0][j] = b; rgb[1][j] = b; }

    #pragma unroll
    for (int half = 0; half < 2; half++) {
        float t[2][32];
        #pragma unroll
        for (int o = 0; o < 32; o++) { float b = W[CB1_O + half*32 + o]; t[0][o] = b; t[1][o] = b; }
        #pragma unroll
        for (int i = 0; i < HID; i++) {
            const float* wr = &W[CW1_O + i*HID + half*32];
            float a = c1[0][i], bq = c1[1][i];
            #pragma unroll
            for (int o = 0; o < 32; o++) { float w = wr[o]; t[0][o] += a*w; t[1][o] += bq*w; }
        }
        #pragma unroll
        for (int o = 0; o < 32; o++) {
            float tA = fmaxf(t[0][o], 0.f);
            float tB = fmaxf(t[1][o], 0.f);
            const float* wr = &W[CW2_O + (half*32 + o)*3];
            #pragma unroll
            for (int j = 0; j < 3; j++) { float w = wr[j]; rgb[0][j] += tA*w; rgb[1][j] += tB*w; }
        }
    }

    f4v* outv = (f4v*)out;
    if (vA) {
        f4v o4; o4.x = sg[0];
        o4.y = 1.f/(1.f+expf(-rgb[0][0]));
        o4.z = 1.f/(1.f+expf(-rgb[0][1]));
        o4.w = 1.f/(1.f+expf(-rgb[0][2]));
        __builtin_nontemporal_store(o4, outv + nA);
    }
    if (vB) {
        f4v o4; o4.x = sg[1];
        o4.y = 1.f/(1.f+expf(-rgb[1][0]));
        o4.z = 1.f/(1.f+expf(-rgb[1][1]));
        o4.w = 1.f/(1.f+expf(-rgb[1][2]));
        __builtin_nontemporal_store(o4, outv + nB);
    }
}

// ======================= Fused fallback (ws too small) =====================
template <int USE_BF16>
__global__ __launch_bounds__(256) void nerf_fused(
    const float* __restrict__ x,
    const float* __restrict__ dvec,
    const int*   __restrict__ app_idx,
    const void*  __restrict__ tbl_raw,
    const float* __restrict__ app_table,
    const float* __restrict__ sw0, const float* __restrict__ sb0,
    const float* __restrict__ sw1, const float* __restrict__ sb1,
    const float* __restrict__ cw0, const float* __restrict__ cb0,
    const float* __restrict__ cw1, const float* __restrict__ cb1,
    const float* __restrict__ cw2, const float* __restrict__ cb2,
    float* __restrict__ out, Res16 rt, int n_pts)
{
    using CT = typename std::conditional<USE_BF16 != 0, unsigned, float2>::type;
    const CT* __restrict__ tbl = (const CT*)tbl_raw;

    int n = blockIdx.x * blockDim.x + threadIdx.x;
    if (n >= n_pts) return;

    float px = (x[3*n+0] + 1.f) * 0.5f;
    float py = (x[3*n+1] + 1.f) * 0.5f;
    float pz = (x[3*n+2] + 1.f) * 0.5f;

    float e[2*NL];
    #pragma unroll
    for (int l = 0; l < NL; l++) {
        float res = rt.r[l];
        float xs = px*res, ys = py*res, zs = pz*res;
        float fx = floorf(xs), fy = floorf(ys), fz = floorf(zs);
        float wx = xs - fx, wy = ys - fy, wz = zs - fz;
        float ax = 1.f - wx, ay = 1.f - wy, az = 1.f - wz;
        unsigned X = (unsigned)fx, Y = (unsigned)fy, Z = (unsigned)fz;
        unsigned hx0 = X,               hx1 = X + 1u;
        unsigned hy0 = Y * 2654435761u, hy1 = hy0 + 2654435761u;
        unsigned hz0 = Z * 805459861u,  hz1 = hz0 + 805459861u;
        const CT* base = tbl + (size_t)l * TBL_N;
        float e0 = 0.f, e1 = 0.f;
        #pragma unroll
        for (int c = 0; c < 8; c++) {
            unsigned idx = (((c & 4) ? hx1 : hx0) ^
                            ((c & 2) ? hy1 : hy0) ^
                            ((c & 1) ? hz1 : hz0)) & (TBL_N - 1u);
            CT v = base[idx];
            float f0, f1;
            corner_vals(v, f0, f1);
            float wgt = ((c & 4) ? wx : ax) * ((c & 2) ? wy : ay) * ((c & 1) ? wz : az);
            e0 += wgt * f0;
            e1 += wgt * f1;
        }
        e[2*l] = e0; e[2*l+1] = e1;
    }

    float h[HID];
    #pragma unroll
    for (int o = 0; o < HID; o++) h[o] = sb0[o];
    #pragma unroll
    for (int l = 0; l < NL; l++) {
        const float* r0 = sw0 + (2 * l) * HID;
        float e0 = e[2*l], e1 = e[2*l+1];
        #pragma unroll
        for (int o = 0; o < HID; o++) h[o] += e0 * r0[o] + e1 * r0[HID + o];
    }
    #pragma unroll
    for (int o = 0; o < HID; o++) h[o] = fmaxf(h[o], 0.f);

    float h1[16];
    #pragma unroll
    for (int o = 0; o < 16; o++) h1[o] = sb1[o];
    #pragma unroll
    for (int i = 0; i < HID; i++) {
        float v = h[i];
        const float* wr = sw1 + i * 16;
        #pragma unroll
        for (int o = 0; o < 16; o++) h1[o] += v * wr[o];
    }

    float z100 = 100.f * h1[0];
    float sigma = (z100 > 20.f) ? h1[0] : (log1pf(expf(z100)) * 0.01f);

    float dx = dvec[3*n+0], dy = dvec[3*n+1], dz = dvec[3*n+2];
    float invn = 1.0f / sqrtf(dx*dx + dy*dy + dz*dz);
    dx *= invn; dy *= invn; dz *= invn;
    float xx = dx*dx, yy = dy*dy, zz = dz*dz;
    float xy = dx*dy, yz = dy*dz, xz = dx*dz;
    float sh[16];
    sh[0]  = 0.28209479177387814f;
    sh[1]  = -0.48860251190291987f * dy;
    sh[2]  =  0.48860251190291987f * dz;
    sh[3]  = -0.48860251190291987f * dx;
    sh[4]  =  1.0925484305920792f * xy;
    sh[5]  = -1.0925484305920792f * yz;
    sh[6]  =  0.94617469575756f * zz - 0.31539156525252005f;
    sh[7]  = -1.0925484305920792f * xz;
    sh[8]  =  0.5462742152960396f * (xx - yy);
    sh[9]  = -0.5900435899266435f * dy * (3.f * xx - yy);
    sh[10] =  2.890611442640554f * xy * dz;
    sh[11] = -0.4570457994644657f * dy * (4.f * zz - xx - yy);
    sh[12] =  0.37317633259011546f * dz * (2.f * zz - 3.f * xx - 3.f * yy);
    sh[13] = -0.4570457994644657f * dx * (4.f * zz - xx - yy);
    sh[14] =  1.445305721320277f * dz * (xx - yy);
    sh[15] = -0.5900435899266435f * dx * (xx - 3.f * yy);

    float c1[HID];
    #pragma unroll
    for (int o = 0; o < HID; o++) c1[o] = cb0[o];
    #pragma unroll
    for (int i = 0; i < 15; i++) {
        float v = h1[i + 1];
        const float* wr = cw0 + i * HID;
        #pragma unroll
        for (int o = 0; o < HID; o++) c1[o] += v * wr[o];
    }
    #pragma unroll
    for (int i = 0; i < 16; i++) {
        float v = sh[i];
        const float* wr = cw0 + (15 + i) * HID;
        #pragma unroll
        for (int o = 0; o < HID; o++) c1[o] += v * wr[o];
    }
    {
        const float4* arow = reinterpret_cast<const float4*>(app_table + (size_t)app_idx[n] * 48);
        for (int j4 = 0; j4 < 12; j4++) {
            float4 v = arow[j4];
            const float* wr = cw0 + (31 + 4 * j4) * HID;
            #pragma unroll
            for (int o = 0; o < HID; o++) c1[o] += v.x * wr[o];
            #pragma unroll
            for (int o = 0; o < HID; o++) c1[o] += v.y * wr[HID + o];
            #pragma unroll
            for (int o = 0; o < HID; o++) c1[o] += v.z * wr[2 * HID + o];
            #pragma unroll
            for (int o = 0; o < HID; o++) c1[o] += v.w * wr[3 * HID + o];
        }
    }
    #pragma unroll
    for (int o = 0; o < HID; o++) c1[o] = fmaxf(c1[o], 0.f);

    float c2[HID];
    #pragma unroll
    for (int o = 0; o < HID; o++) c2[o] = cb1[o];
    #pragma unroll
    for (int i = 0; i < HID; i++) {
        float v = c1[i];
        const float* wr = cw1 + i * HID;
        #pragma unroll
        for (int o = 0; o < HID; o++) c2[o] += v * wr[o];
    }
    #pragma unroll
    for (int o = 0; o < HID; o++) c2[o] = fmaxf(c2[o], 0.f);

    float r = cb2[0], g = cb2[1], b = cb2[2];
    #pragma unroll
    for (int i = 0; i < HID; i++) {
        float v = c2[i];
        r += v * cw2[i * 3 + 0];
        g += v * cw2[i * 3 + 1];
        b += v * cw2[i * 3 + 2];
    }
    r = 1.f / (1.f + expf(-r));
    g = 1.f / (1.f + expf(-g));
    b = 1.f / (1.f + expf(-b));

    reinterpret_cast<float4*>(out)[n] = make_float4(sigma, r, g, b);
}

extern "C" void kernel_launch(void* const* d_in, const int* in_sizes, int n_in,
                              void* d_out, int out_size, void* d_ws, size_t ws_size,
                              hipStream_t stream) {
    const float* x         = (const float*)d_in[0];
    const float* dvec      = (const float*)d_in[1];
    const int*   app_idx   = (const int*)  d_in[2];
    const float* ht        = (const float*)d_in[3];
    const float* app_table = (const float*)d_in[4];
    const float* sw0 = (const float*)d_in[5];
    const float* sb0 = (const float*)d_in[6];
    const float* sw1 = (const float*)d_in[7];
    const float* sb1 = (const float*)d_in[8];
    const float* cw0 = (const float*)d_in[9];
    const float* cb0 = (const float*)d_in[10];
    const float* cw1 = (const float*)d_in[11];
    const float* cb1 = (const float*)d_in[12];
    const float* cw2 = (const float*)d_in[13];
    const float* cb2 = (const float*)d_in[14];

    int n_pts = in_sizes[0] / 3;

    Res16 rt;
    double bb = exp(log(2048.0 / 16.0) / 15.0);
    for (int l = 0; l < NL; l++) rt.r[l] = (float)floor(16.0 * pow(bb, (double)l));

    const size_t tbl_entries = (size_t)NL * TBL_N;
    const size_t tbl_bytes = tbl_entries * sizeof(unsigned);       // 32 MiB

    if (ws_size >= tbl_bytes + (4u << 20)) {
        int nent = (int)tbl_entries;
        hipLaunchKernelGGL(repack_bf16, dim3((nent + 255) / 256), dim3(256), 0, stream,
                           ht, (unsigned*)d_ws, nent);

        size_t cap = (ws_size - tbl_bytes) / (NL * sizeof(unsigned));
        if (cap > (size_t)n_pts) cap = (size_t)n_pts;
        cap &= ~(size_t)511;
        if (cap == 0) cap = 512;
        unsigned* enc = (unsigned*)((char*)d_ws + tbl_bytes);

        for (long p0 = 0; p0 < (long)n_pts; p0 += (long)cap) {
            int P = (int)(((long)n_pts - p0) < (long)cap ? ((long)n_pts - p0) : (long)cap);
            hipLaunchKernelGGL(nerf_encode, dim3((P + 255) / 256), dim3(256), 0, stream,
                               x, (const unsigned*)d_ws, enc, rt, (int)p0, P, n_pts);
            hipLaunchKernelGGL(nerf_mlp, dim3((P + 511) / 512), dim3(256), 0, stream,
                               enc, dvec, app_idx, app_table,
                               sw0, sb0, sw1, sb1, cw0, cb0, cw1, cb1, cw2, cb2,
                               (float*)d_out, (int)p0, P, n_pts);
        }
    } else if (ws_size >= tbl_bytes) {
        int nent = (int)tbl_entries;
        hipLaunchKernelGGL(repack_bf16, dim3((nent + 255) / 256), dim3(256), 0, stream,
                           ht, (unsigned*)d_ws, nent);
        dim3 g((n_pts + 255) / 256), blk(256);
        hipLaunchKernelGGL((nerf_fused<1>), g, blk, 0, stream,
                           x, dvec, app_idx, (const void*)d_ws, app_table,
                           sw0, sb0, sw1, sb1, cw0, cb0, cw1, cb1, cw2, cb2,
                           (float*)d_out, rt, n_pts);
    } else {
        dim3 g((n_pts + 255) / 256), blk(256);
        hipLaunchKernelGGL((nerf_fused<0>), g, blk, 0, stream,
                           x, dvec, app_idx, (const void*)ht, app_table,
                           sw0, sb0, sw1, sb1, cw0, cb0, cw1, cb1, cw2, cb2,
                           (float*)d_out, rt, n_pts);
    }
}

// Round 7
// 8627.766 us; speedup vs baseline: 2.2355x; 2.2355x over previous
//
#include <hip/hip_runtime.h>
#include <cmath>
#include <type_traits>

#define NL 16
#define TBL_N (1u << 19)
#define HID 64

typedef float f4v __attribute__((ext_vector_type(4)));
typedef float f2v __attribute__((ext_vector_type(2)));

struct Res16 { float r[NL]; };

__device__ __forceinline__ unsigned short f2bf(float f) {
    unsigned u = __float_as_uint(f);
    unsigned r = (u + 0x7FFFu + ((u >> 16) & 1u)) >> 16;   // RNE
    return (unsigned short)r;
}
__device__ __forceinline__ unsigned pack_bf(float a, float b) {
    return (unsigned)f2bf(a) | ((unsigned)f2bf(b) << 16);
}
__device__ __forceinline__ void corner_vals(unsigned v, float& f0, float& f1) {
    f0 = __uint_as_float(v << 16);
    f1 = __uint_as_float(v & 0xffff0000u);
}
__device__ __forceinline__ void corner_vals(float2 v, float& f0, float& f1) {
    f0 = v.x; f1 = v.y;
}

__global__ __launch_bounds__(256) void repack_bf16(const float* __restrict__ src,
                                                   unsigned* __restrict__ dst, int n) {
    int i = blockIdx.x * blockDim.x + threadIdx.x;
    if (i >= n) return;
    f2v v = __builtin_nontemporal_load((const f2v*)src + i);
    dst[i] = pack_bf(v.x, v.y);
}

// ======================= Kernel E: hash-grid encode ========================
__global__ __launch_bounds__(256) void nerf_encode(
    const float* __restrict__ x,
    const unsigned* __restrict__ tbl,
    unsigned* __restrict__ enc,
    Res16 rt, int p0, int P, int n_pts)
{
    int p = blockIdx.x * blockDim.x + threadIdx.x;
    if (p >= P) return;
    int n = p0 + p;
    if (n >= n_pts) return;

    float px = (__builtin_nontemporal_load(&x[3*n+0]) + 1.f) * 0.5f;
    float py = (__builtin_nontemporal_load(&x[3*n+1]) + 1.f) * 0.5f;
    float pz = (__builtin_nontemporal_load(&x[3*n+2]) + 1.f) * 0.5f;

    #pragma unroll 4
    for (int l = 0; l < NL; l++) {
        float res = rt.r[l];
        float xs = px*res, ys = py*res, zs = pz*res;
        float fx = floorf(xs), fy = floorf(ys), fz = floorf(zs);
        float wx = xs - fx, wy = ys - fy, wz = zs - fz;
        float ax = 1.f - wx, ay = 1.f - wy, az = 1.f - wz;
        unsigned X = (unsigned)fx, Y = (unsigned)fy, Z = (unsigned)fz;
        unsigned hx0 = X,               hx1 = X + 1u;
        unsigned hy0 = Y * 2654435761u, hy1 = hy0 + 2654435761u;
        unsigned hz0 = Z * 805459861u,  hz1 = hz0 + 805459861u;
        const unsigned* base = tbl + (size_t)l * TBL_N;

        float e0 = 0.f, e1 = 0.f;
        #pragma unroll
        for (int c = 0; c < 8; c++) {
            unsigned idx = (((c & 4) ? hx1 : hx0) ^
                            ((c & 2) ? hy1 : hy0) ^
                            ((c & 1) ? hz1 : hz0)) & (TBL_N - 1u);
            unsigned v = base[idx];
            float f0, f1;
            corner_vals(v, f0, f1);
            float wgt = ((c & 4) ? wx : ax) * ((c & 2) ? wy : ay) * ((c & 1) ? wz : az);
            e0 += wgt * f0;
            e1 += wgt * f1;
        }
        __builtin_nontemporal_store(pack_bf(e0, e1), &enc[(size_t)l * P + p]);
    }
}

// ======================= Kernel M: LDS weights, 1 pt/thread ================
#define SW0_O 0
#define SB0_O 2048
#define SW1_O 2112
#define SB1_O 3136
#define CW0_O 3152
#define CB0_O 8208
#define CW1_O 8272
#define CB1_O 12368
#define CW2_O 12432
#define CB2_O 12624
#define WTOT  12628

__global__ __launch_bounds__(256) void nerf_mlp(
    const unsigned* __restrict__ enc,
    const float* __restrict__ dvec,
    const int*   __restrict__ app_idx,
    const float* __restrict__ app_table,
    const float* __restrict__ sw0, const float* __restrict__ sb0,
    const float* __restrict__ sw1, const float* __restrict__ sb1,
    const float* __restrict__ cw0, const float* __restrict__ cb0,
    const float* __restrict__ cw1, const float* __restrict__ cb1,
    const float* __restrict__ cw2, const float* __restrict__ cb2,
    float* __restrict__ out, int p0, int P, int n_pts)
{
    __shared__ __align__(16) float W[WTOT];
    int tid = threadIdx.x;
    for (int i = tid; i < 2048; i += 256) W[SW0_O+i] = sw0[i];
    for (int i = tid; i < 64;   i += 256) W[SB0_O+i] = sb0[i];
    for (int i = tid; i < 1024; i += 256) W[SW1_O+i] = sw1[i];
    if (tid < 16) W[SB1_O+tid] = sb1[tid];
    for (int i = tid; i < 5056; i += 256) W[CW0_O+i] = cw0[i];
    for (int i = tid; i < 64;   i += 256) W[CB0_O+i] = cb0[i];
    for (int i = tid; i < 4096; i += 256) W[CW1_O+i] = cw1[i];
    for (int i = tid; i < 64;   i += 256) W[CB1_O+i] = cb1[i];
    for (int i = tid; i < 192;  i += 256) W[CW2_O+i] = cw2[i];
    if (tid < 3) W[CB2_O+tid] = cb2[tid];
    __syncthreads();

    int p = blockIdx.x * blockDim.x + tid;
    if (p >= P) return;
    int n = p0 + p;
    if (n >= n_pts) return;

    // ---- density layer 0 ----
    float h[HID];
    #pragma unroll
    for (int o = 0; o < HID; o++) h[o] = W[SB0_O+o];
    const unsigned* ep = enc + p;
    #pragma unroll
    for (int l = 0; l < NL; l++) {
        unsigned u = __builtin_nontemporal_load(ep + (size_t)l * P);
        float e0, e1;
        corner_vals(u, e0, e1);
        const float* r0 = &W[SW0_O + 2*l*HID];
        #pragma unroll
        for (int o = 0; o < HID; o++) h[o] += e0 * r0[o] + e1 * r0[HID+o];
    }
    #pragma unroll
    for (int o = 0; o < HID; o++) h[o] = fmaxf(h[o], 0.f);

    // ---- density layer 1 ----
    float h1[16];
    #pragma unroll
    for (int o = 0; o < 16; o++) h1[o] = W[SB1_O+o];
    #pragma unroll
    for (int i = 0; i < HID; i++) {
        const float* wr = &W[SW1_O + i*16];
        float a = h[i];
        #pragma unroll
        for (int o = 0; o < 16; o++) h1[o] += a * wr[o];
    }

    float z100 = 100.f * h1[0];
    float sigma = (z100 > 20.f) ? h1[0] : (log1pf(expf(z100)) * 0.01f);

    // ---- color layer 0 ----
    float c1[HID];
    #pragma unroll
    for (int o = 0; o < HID; o++) c1[o] = W[CB0_O+o];
    #pragma unroll
    for (int i = 0; i < 15; i++) {
        const float* wr = &W[CW0_O + i*HID];
        float a = h1[i+1];
        #pragma unroll
        for (int o = 0; o < HID; o++) c1[o] += a * wr[o];
    }

    // ---- SH rows ----
    {
        float dx = __builtin_nontemporal_load(&dvec[3*n+0]);
        float dy = __builtin_nontemporal_load(&dvec[3*n+1]);
        float dz = __builtin_nontemporal_load(&dvec[3*n+2]);
        float invn = 1.0f / sqrtf(dx*dx + dy*dy + dz*dz);
        dx *= invn; dy *= invn; dz *= invn;
        float xx = dx*dx, yy = dy*dy, zz = dz*dz;
        float xy = dx*dy, yz = dy*dz, xz = dx*dz;
        float shv[16];
        shv[0]  = 0.28209479177387814f;
        shv[1]  = -0.48860251190291987f * dy;
        shv[2]  =  0.48860251190291987f * dz;
        shv[3]  = -0.48860251190291987f * dx;
        shv[4]  =  1.0925484305920792f * xy;
        shv[5]  = -1.0925484305920792f * yz;
        shv[6]  =  0.94617469575756f * zz - 0.31539156525252005f;
        shv[7]  = -1.0925484305920792f * xz;
        shv[8]  =  0.5462742152960396f * (xx - yy);
        shv[9]  = -0.5900435899266435f * dy * (3.f * xx - yy);
        shv[10] =  2.890611442640554f * xy * dz;
        shv[11] = -0.4570457994644657f * dy * (4.f * zz - xx - yy);
        shv[12] =  0.37317633259011546f * dz * (2.f * zz - 3.f * xx - 3.f * yy);
        shv[13] = -0.4570457994644657f * dx * (4.f * zz - xx - yy);
        shv[14] =  1.445305721320277f * dz * (xx - yy);
        shv[15] = -0.5900435899266435f * dx * (xx - 3.f * yy);
        #pragma unroll
        for (int i = 0; i < 16; i++) {
            const float* wr = &W[CW0_O + (15+i)*HID];
            float a = shv[i];
            #pragma unroll
            for (int o = 0; o < HID; o++) c1[o] += a * wr[o];
        }
    }

    // ---- app rows ----
    {
        int ai = __builtin_nontemporal_load(&app_idx[n]);
        const f4v* row = (const f4v*)(app_table + (size_t)ai * 48);
        for (int j4 = 0; j4 < 12; j4++) {          // rolled: activations from memory
            f4v a4 = row[j4];
            const float* wr = &W[CW0_O + (31 + 4*j4)*HID];
            #pragma unroll
            for (int k = 0; k < 4; k++) {
                float a = a4[k];
                const float* wk = wr + k*HID;
                #pragma unroll
                for (int o = 0; o < HID; o++) c1[o] += a * wk[o];
            }
        }
    }
    #pragma unroll
    for (int o = 0; o < HID; o++) c1[o] = fmaxf(c1[o], 0.f);

    // ---- color layers 1+2, 32-wide halves ----
    float rgb[3];
    #pragma unroll
    for (int j = 0; j < 3; j++) rgb[j] = W[CB2_O+j];

    #pragma unroll
    for (int half = 0; half < 2; half++) {
        float t[32];
        #pragma unroll
        for (int o = 0; o < 32; o++) t[o] = W[CB1_O + half*32 + o];
        #pragma unroll
        for (int i = 0; i < HID; i++) {
            const float* wr = &W[CW1_O + i*HID + half*32];
            float a = c1[i];
            #pragma unroll
            for (int o = 0; o < 32; o++) t[o] += a * wr[o];
        }
        #pragma unroll
        for (int o = 0; o < 32; o++) {
            float tv = fmaxf(t[o], 0.f);
            const float* wr = &W[CW2_O + (half*32 + o)*3];
            #pragma unroll
            for (int j = 0; j < 3; j++) rgb[j] += tv * wr[j];
        }
    }

    f4v o4;
    o4.x = sigma;
    o4.y = 1.f/(1.f+expf(-rgb[0]));
    o4.z = 1.f/(1.f+expf(-rgb[1]));
    o4.w = 1.f/(1.f+expf(-rgb[2]));
    __builtin_nontemporal_store(o4, (f4v*)out + n);
}

// ======================= Fused fallback (ws too small) =====================
template <int USE_BF16>
__global__ __launch_bounds__(256) void nerf_fused(
    const float* __restrict__ x,
    const float* __restrict__ dvec,
    const int*   __restrict__ app_idx,
    const void*  __restrict__ tbl_raw,
    const float* __restrict__ app_table,
    const float* __restrict__ sw0, const float* __restrict__ sb0,
    const float* __restrict__ sw1, const float* __restrict__ sb1,
    const float* __restrict__ cw0, const float* __restrict__ cb0,
    const float* __restrict__ cw1, const float* __restrict__ cb1,
    const float* __restrict__ cw2, const float* __restrict__ cb2,
    float* __restrict__ out, Res16 rt, int n_pts)
{
    using CT = typename std::conditional<USE_BF16 != 0, unsigned, float2>::type;
    const CT* __restrict__ tbl = (const CT*)tbl_raw;

    int n = blockIdx.x * blockDim.x + threadIdx.x;
    if (n >= n_pts) return;

    float px = (x[3*n+0] + 1.f) * 0.5f;
    float py = (x[3*n+1] + 1.f) * 0.5f;
    float pz = (x[3*n+2] + 1.f) * 0.5f;

    float e[2*NL];
    #pragma unroll
    for (int l = 0; l < NL; l++) {
        float res = rt.r[l];
        float xs = px*res, ys = py*res, zs = pz*res;
        float fx = floorf(xs), fy = floorf(ys), fz = floorf(zs);
        float wx = xs - fx, wy = ys - fy, wz = zs - fz;
        float ax = 1.f - wx, ay = 1.f - wy, az = 1.f - wz;
        unsigned X = (unsigned)fx, Y = (unsigned)fy, Z = (unsigned)fz;
        unsigned hx0 = X,               hx1 = X + 1u;
        unsigned hy0 = Y * 2654435761u, hy1 = hy0 + 2654435761u;
        unsigned hz0 = Z * 805459861u,  hz1 = hz0 + 805459861u;
        const CT* base = tbl + (size_t)l * TBL_N;
        float e0 = 0.f, e1 = 0.f;
        #pragma unroll
        for (int c = 0; c < 8; c++) {
            unsigned idx = (((c & 4) ? hx1 : hx0) ^
                            ((c & 2) ? hy1 : hy0) ^
                            ((c & 1) ? hz1 : hz0)) & (TBL_N - 1u);
            CT v = base[idx];
            float f0, f1;
            corner_vals(v, f0, f1);
            float wgt = ((c & 4) ? wx : ax) * ((c & 2) ? wy : ay) * ((c & 1) ? wz : az);
            e0 += wgt * f0;
            e1 += wgt * f1;
        }
        e[2*l] = e0; e[2*l+1] = e1;
    }

    float h[HID];
    #pragma unroll
    for (int o = 0; o < HID; o++) h[o] = sb0[o];
    #pragma unroll
    for (int l = 0; l < NL; l++) {
        const float* r0 = sw0 + (2 * l) * HID;
        float e0 = e[2*l], e1 = e[2*l+1];
        #pragma unroll
        for (int o = 0; o < HID; o++) h[o] += e0 * r0[o] + e1 * r0[HID + o];
    }
    #pragma unroll
    for (int o = 0; o < HID; o++) h[o] = fmaxf(h[o], 0.f);

    float h1[16];
    #pragma unroll
    for (int o = 0; o < 16; o++) h1[o] = sb1[o];
    #pragma unroll
    for (int i = 0; i < HID; i++) {
        float v = h[i];
        const float* wr = sw1 + i * 16;
        #pragma unroll
        for (int o = 0; o < 16; o++) h1[o] += v * wr[o];
    }

    float z100 = 100.f * h1[0];
    float sigma = (z100 > 20.f) ? h1[0] : (log1pf(expf(z100)) * 0.01f);

    float dx = dvec[3*n+0], dy = dvec[3*n+1], dz = dvec[3*n+2];
    float invn = 1.0f / sqrtf(dx*dx + dy*dy + dz*dz);
    dx *= invn; dy *= invn; dz *= invn;
    float xx = dx*dx, yy = dy*dy, zz = dz*dz;
    float xy = dx*dy, yz = dy*dz, xz = dx*dz;
    float sh[16];
    sh[0]  = 0.28209479177387814f;
    sh[1]  = -0.48860251190291987f * dy;
    sh[2]  =  0.48860251190291987f * dz;
    sh[3]  = -0.48860251190291987f * dx;
    sh[4]  =  1.0925484305920792f * xy;
    sh[5]  = -1.0925484305920792f * yz;
    sh[6]  =  0.94617469575756f * zz - 0.31539156525252005f;
    sh[7]  = -1.0925484305920792f * xz;
    sh[8]  =  0.5462742152960396f * (xx - yy);
    sh[9]  = -0.5900435899266435f * dy * (3.f * xx - yy);
    sh[10] =  2.890611442640554f * xy * dz;
    sh[11] = -0.4570457994644657f * dy * (4.f * zz - xx - yy);
    sh[12] =  0.37317633259011546f * dz * (2.f * zz - 3.f * xx - 3.f * yy);
    sh[13] = -0.4570457994644657f * dx * (4.f * zz - xx - yy);
    sh[14] =  1.445305721320277f * dz * (xx - yy);
    sh[15] = -0.5900435899266435f * dx * (xx - 3.f * yy);

    float c1[HID];
    #pragma unroll
    for (int o = 0; o < HID; o++) c1[o] = cb0[o];
    #pragma unroll
    for (int i = 0; i < 15; i++) {
        float v = h1[i + 1];
        const float* wr = cw0 + i * HID;
        #pragma unroll
        for (int o = 0; o < HID; o++) c1[o] += v * wr[o];
    }
    #pragma unroll
    for (int i = 0; i < 16; i++) {
        float v = sh[i];
        const float* wr = cw0 + (15 + i) * HID;
        #pragma unroll
        for (int o = 0; o < HID; o++) c1[o] += v * wr[o];
    }
    {
        const float4* arow = reinterpret_cast<const float4*>(app_table + (size_t)app_idx[n] * 48);
        for (int j4 = 0; j4 < 12; j4++) {
            float4 v = arow[j4];
            const float* wr = cw0 + (31 + 4 * j4) * HID;
            #pragma unroll
            for (int o = 0; o < HID; o++) c1[o] += v.x * wr[o];
            #pragma unroll
            for (int o = 0; o < HID; o++) c1[o] += v.y * wr[HID + o];
            #pragma unroll
            for (int o = 0; o < HID; o++) c1[o] += v.z * wr[2 * HID + o];
            #pragma unroll
            for (int o = 0; o < HID; o++) c1[o] += v.w * wr[3 * HID + o];
        }
    }
    #pragma unroll
    for (int o = 0; o < HID; o++) c1[o] = fmaxf(c1[o], 0.f);

    float c2[HID];
    #pragma unroll
    for (int o = 0; o < HID; o++) c2[o] = cb1[o];
    #pragma unroll
    for (int i = 0; i < HID; i++) {
        float v = c1[i];
        const float* wr = cw1 + i * HID;
        #pragma unroll
        for (int o = 0; o < HID; o++) c2[o] += v * wr[o];
    }
    #pragma unroll
    for (int o = 0; o < HID; o++) c2[o] = fmaxf(c2[o], 0.f);

    float r = cb2[0], g = cb2[1], b = cb2[2];
    #pragma unroll
    for (int i = 0; i < HID; i++) {
        float v = c2[i];
        r += v * cw2[i * 3 + 0];
        g += v * cw2[i * 3 + 1];
        b += v * cw2[i * 3 + 2];
    }
    r = 1.f / (1.f + expf(-r));
    g = 1.f / (1.f + expf(-g));
    b = 1.f / (1.f + expf(-b));

    reinterpret_cast<float4*>(out)[n] = make_float4(sigma, r, g, b);
}

extern "C" void kernel_launch(void* const* d_in, const int* in_sizes, int n_in,
                              void* d_out, int out_size, void* d_ws, size_t ws_size,
                              hipStream_t stream) {
    const float* x         = (const float*)d_in[0];
    const float* dvec      = (const float*)d_in[1];
    const int*   app_idx   = (const int*)  d_in[2];
    const float* ht        = (const float*)d_in[3];
    const float* app_table = (const float*)d_in[4];
    const float* sw0 = (const float*)d_in[5];
    const float* sb0 = (const float*)d_in[6];
    const float* sw1 = (const float*)d_in[7];
    const float* sb1 = (const float*)d_in[8];
    const float* cw0 = (const float*)d_in[9];
    const float* cb0 = (const float*)d_in[10];
    const float* cw1 = (const float*)d_in[11];
    const float* cb1 = (const float*)d_in[12];
    const float* cw2 = (const float*)d_in[13];
    const float* cb2 = (const float*)d_in[14];

    int n_pts = in_sizes[0] / 3;

    Res16 rt;
    double bb = exp(log(2048.0 / 16.0) / 15.0);
    for (int l = 0; l < NL; l++) rt.r[l] = (float)floor(16.0 * pow(bb, (double)l));

    const size_t tbl_entries = (size_t)NL * TBL_N;
    const size_t tbl_bytes = tbl_entries * sizeof(unsigned);       // 32 MiB

    if (ws_size >= tbl_bytes + (4u << 20)) {
        int nent = (int)tbl_entries;
        hipLaunchKernelGGL(repack_bf16, dim3((nent + 255) / 256), dim3(256), 0, stream,
                           ht, (unsigned*)d_ws, nent);

        size_t cap = (ws_size - tbl_bytes) / (NL * sizeof(unsigned));
        if (cap > (size_t)n_pts) cap = (size_t)n_pts;
        cap &= ~(size_t)255;
        if (cap == 0) cap = 256;
        unsigned* enc = (unsigned*)((char*)d_ws + tbl_bytes);

        for (long p0 = 0; p0 < (long)n_pts; p0 += (long)cap) {
            int P = (int)(((long)n_pts - p0) < (long)cap ? ((long)n_pts - p0) : (long)cap);
            dim3 g((P + 255) / 256), blk(256);
            hipLaunchKernelGGL(nerf_encode, g, blk, 0, stream,
                               x, (const unsigned*)d_ws, enc, rt, (int)p0, P, n_pts);
            hipLaunchKernelGGL(nerf_mlp, g, blk, 0, stream,
                               enc, dvec, app_idx, app_table,
                               sw0, sb0, sw1, sb1, cw0, cb0, cw1, cb1, cw2, cb2,
                               (float*)d_out, (int)p0, P, n_pts);
        }
    } else if (ws_size >= tbl_bytes) {
        int nent = (int)tbl_entries;
        hipLaunchKernelGGL(repack_bf16, dim3((nent + 255) / 256), dim3(256), 0, stream,
                           ht, (unsigned*)d_ws, nent);
        dim3 g((n_pts + 255) / 256), blk(256);
        hipLaunchKernelGGL((nerf_fused<1>), g, blk, 0, stream,
                           x, dvec, app_idx, (const void*)d_ws, app_table,
                           sw0, sb0, sw1, sb1, cw0, cb0, cw1, cb1, cw2, cb2,
                           (float*)d_out, rt, n_pts);
    } else {
        dim3 g((n_pts + 255) / 256), blk(256);
        hipLaunchKernelGGL((nerf_fused<0>), g, blk, 0, stream,
                           x, dvec, app_idx, (const void*)ht, app_table,
                           sw0, sb0, sw1, sb1, cw0, cb0, cw1, cb1, cw2, cb2,
                           (float*)d_out, rt, n_pts);
    }
}

// Round 8
// 2332.394 us; speedup vs baseline: 8.2693x; 3.6991x over previous
//
#include <hip/hip_runtime.h>
#include <cmath>
#include <type_traits>

#define NL 16
#define TBL_N (1u << 19)
#define HID 64

typedef float f4v __attribute__((ext_vector_type(4)));
typedef float f2v __attribute__((ext_vector_type(2)));
typedef short s8v __attribute__((ext_vector_type(8)));
typedef unsigned int u32;
typedef unsigned short u16;

struct Res16 { float r[NL]; };

__device__ __host__ __forceinline__ unsigned short f2bf(float f) {
    unsigned u = __builtin_bit_cast(unsigned, f);
    unsigned r = (u + 0x7FFFu + ((u >> 16) & 1u)) >> 16;   // RNE
    return (unsigned short)r;
}
__device__ __forceinline__ u32 pack_bf(float a, float b) {
    return (u32)f2bf(a) | ((u32)f2bf(b) << 16);
}
__device__ __forceinline__ void corner_vals(unsigned v, float& f0, float& f1) {
    f0 = __uint_as_float(v << 16);
    f1 = __uint_as_float(v & 0xffff0000u);
}
__device__ __forceinline__ void corner_vals(float2 v, float& f0, float& f1) {
    f0 = v.x; f1 = v.y;
}

__global__ __launch_bounds__(256) void repack_bf16(const float* __restrict__ src,
                                                   unsigned* __restrict__ dst, int n) {
    int i = blockIdx.x * blockDim.x + threadIdx.x;
    if (i >= n) return;
    f2v v = __builtin_nontemporal_load((const f2v*)src + i);
    dst[i] = pack_bf(v.x, v.y);
}

// ======================= Kernel E: hash-grid encode ========================
// Writes enc POINT-MAJOR (16 dwords = 32 bf16 per point), LDS-transposed for
// coalesced stores.
__global__ __launch_bounds__(256) void nerf_encode(
    const float* __restrict__ x,
    const unsigned* __restrict__ tbl,
    u32* __restrict__ enc,
    Res16 rt, int p0, int P, int n_pts)
{
    __shared__ u32 S[256 * 17];
    int tid = threadIdx.x;
    int p = blockIdx.x * 256 + tid;
    int pc = min(p, P - 1);
    int n = p0 + pc;

    float px = (__builtin_nontemporal_load(&x[3*n+0]) + 1.f) * 0.5f;
    float py = (__builtin_nontemporal_load(&x[3*n+1]) + 1.f) * 0.5f;
    float pz = (__builtin_nontemporal_load(&x[3*n+2]) + 1.f) * 0.5f;

    #pragma unroll 4
    for (int l = 0; l < NL; l++) {
        float res = rt.r[l];
        float xs = px*res, ys = py*res, zs = pz*res;
        float fx = floorf(xs), fy = floorf(ys), fz = floorf(zs);
        float wx = xs - fx, wy = ys - fy, wz = zs - fz;
        float ax = 1.f - wx, ay = 1.f - wy, az = 1.f - wz;
        unsigned X = (unsigned)fx, Y = (unsigned)fy, Z = (unsigned)fz;
        unsigned hx0 = X,               hx1 = X + 1u;
        unsigned hy0 = Y * 2654435761u, hy1 = hy0 + 2654435761u;
        unsigned hz0 = Z * 805459861u,  hz1 = hz0 + 805459861u;
        const unsigned* base = tbl + (size_t)l * TBL_N;

        float e0 = 0.f, e1 = 0.f;
        #pragma unroll
        for (int c = 0; c < 8; c++) {
            unsigned idx = (((c & 4) ? hx1 : hx0) ^
                            ((c & 2) ? hy1 : hy0) ^
                            ((c & 1) ? hz1 : hz0)) & (TBL_N - 1u);
            unsigned v = base[idx];
            float f0, f1;
            corner_vals(v, f0, f1);
            float wgt = ((c & 4) ? wx : ax) * ((c & 2) ? wy : ay) * ((c & 1) ? wz : az);
            e0 += wgt * f0;
            e1 += wgt * f1;
        }
        S[tid * 17 + l] = pack_bf(e0, e1);
    }
    __syncthreads();
    int base = blockIdx.x * 4096;
    #pragma unroll
    for (int k = 0; k < 16; k++) {
        int idx = k * 256 + tid;
        int pp = idx >> 4, t = idx & 15;
        if (blockIdx.x * 256 + pp < P)
            __builtin_nontemporal_store(S[pp * 17 + t], &enc[base + idx]);
    }
}

// ======================= Pack weights into MFMA A-fragments ================
// Frag ids: L0: 0..3 (mt); L1: 4..5 (kt); C0: 6..17 (mt*3+kt);
//           C1: 18..25 (mt*2+kt); C2: 26..27 (kt).
// Frag element (lane,j) = W[featout = mt*16 + (lane&15)][featin = kt*32 + (lane>>4)*8 + j]
// C0 featin order permuted to [sh(0..15), app(16..63), geo(64..78), pad(79..95)].
__global__ __launch_bounds__(256) void nerf_pack_w(
    const float* __restrict__ sw0, const float* __restrict__ sb0,
    const float* __restrict__ sw1, const float* __restrict__ sb1,
    const float* __restrict__ cw0, const float* __restrict__ cb0,
    const float* __restrict__ cw1, const float* __restrict__ cb1,
    const float* __restrict__ cw2, const float* __restrict__ cb2,
    u16* __restrict__ wf, float* __restrict__ bi)
{
    int tid = threadIdx.x;
    for (int e = tid; e < 14336; e += 256) {
        int f = e >> 9, r = e & 511, lane = r >> 3, j = r & 7;
        int fo = lane & 15, G = lane >> 4;
        float val = 0.f;
        if (f < 4) {                       // L0: W = sw0^T, K=32
            int o = f*16 + fo, i = G*8 + j;
            val = sw0[i*64 + o];
        } else if (f < 6) {                // L1: K=64, M=16
            int o = fo, i = (f-4)*32 + G*8 + j;
            val = sw1[i*16 + o];
        } else if (f < 18) {               // C0: K=96 permuted
            int t = f - 6, mt = t / 3, kt = t % 3;
            int o = mt*16 + fo, i = kt*32 + G*8 + j;
            int row = (i < 16) ? (15 + i) : (i < 64) ? (31 + (i - 16)) : (i < 79) ? (i - 64) : -1;
            val = (row < 0) ? 0.f : cw0[row*64 + o];
        } else if (f < 26) {               // C1: K=64
            int t = f - 18, mt = t >> 1, kt = t & 1;
            int o = mt*16 + fo, i = kt*32 + G*8 + j;
            val = cw1[i*64 + o];
        } else {                           // C2: M=16 (3 real), K=64
            int kt = f - 26;
            int o = fo, i = kt*32 + G*8 + j;
            val = (o < 3) ? cw2[i*3 + o] : 0.f;
        }
        wf[e] = f2bf(val);
    }
    for (int i2 = tid; i2 < 224; i2 += 256) {
        float v;
        if (i2 < 64) v = sb0[i2];
        else if (i2 < 80) v = sb1[i2 - 64];
        else if (i2 < 144) v = cb0[i2 - 80];
        else if (i2 < 208) v = cb1[i2 - 144];
        else v = (i2 - 208 < 3) ? cb2[i2 - 208] : 0.f;
        bi[i2] = v;
    }
}

// ======================= Kernel M: MFMA MLP ================================
// 256 threads = 4 waves x 16 points. Activations always B-operand
// (col = lane&15 = point, k = feature, 8 contiguous per lane-group).
#define ASTRIDE 104   // ushorts per point row in ACT (>=96, 16B-multiple)

__global__ __launch_bounds__(256) void nerf_mlp_mfma(
    const u16* __restrict__ wfg, const float* __restrict__ big,
    const u16* __restrict__ enc16,
    const float* __restrict__ dvec, const int* __restrict__ app_idx,
    const float* __restrict__ app_table,
    float* __restrict__ out, int p0, int P, int n_pts)
{
    __shared__ __align__(16) u16 WF[14336];
    __shared__ __align__(16) float BI[224];
    __shared__ __align__(16) u16 ACT[4][16 * ASTRIDE];

    int tid = threadIdx.x;
    int w = tid >> 6, l = tid & 63;
    int G = l >> 4, pq = l & 15;
    int pl = blockIdx.x * 64 + w * 16 + pq;
    int pc = min(pl, P - 1);
    int n = p0 + pc;

    // early streaming loads (overlap with staging)
    s8v encf = __builtin_nontemporal_load((const s8v*)(enc16 + (size_t)pc * 32 + G * 8));
    float dx = __builtin_nontemporal_load(&dvec[3*n+0]);
    float dy = __builtin_nontemporal_load(&dvec[3*n+1]);
    float dz = __builtin_nontemporal_load(&dvec[3*n+2]);
    int ai = app_idx[n];
    const f4v* arow = (const f4v*)(app_table + (size_t)ai * 48 + 12 * G);
    f4v a0 = arow[0], a1 = arow[1], a2 = arow[2];

    // stage fragments + biases
    for (int i = tid; i < 1792; i += 256) ((uint4*)WF)[i] = ((const uint4*)wfg)[i];
    for (int i = tid; i < 224; i += 256) BI[i] = big[i];
    // zero pad region (feats 79..95) once
    if (G == 3) {
        ACT[w][pq*ASTRIDE + 79] = 0;
        #pragma unroll
        for (int k = 0; k < 8; k++) *(u32*)&ACT[w][pq*ASTRIDE + 80 + 2*k] = 0u;
    }
    __syncthreads();

    // ---- L0: h = relu(enc @ sw0 + sb0)  (M=64 featout, K=32) ----
    f4v acc0[4];
    #pragma unroll
    for (int mt = 0; mt < 4; mt++) acc0[mt] = *(const f4v*)&BI[mt*16 + 4*G];
    #pragma unroll
    for (int mt = 0; mt < 4; mt++) {
        s8v wfr = *(const s8v*)&WF[mt*512 + l*8];
        acc0[mt] = __builtin_amdgcn_mfma_f32_16x16x32_bf16(wfr, encf, acc0[mt], 0, 0, 0);
    }
    #pragma unroll
    for (int mt = 0; mt < 4; mt++) {
        f4v v = acc0[mt];
        *(u32*)&ACT[w][pq*ASTRIDE + mt*16 + 4*G]     = pack_bf(fmaxf(v[0],0.f), fmaxf(v[1],0.f));
        *(u32*)&ACT[w][pq*ASTRIDE + mt*16 + 4*G + 2] = pack_bf(fmaxf(v[2],0.f), fmaxf(v[3],0.f));
    }

    // ---- L1: h1 = h @ sw1 + sb1 (M=16, K=64), raw (no relu) ----
    f4v acc1 = *(const f4v*)&BI[64 + 4*G];
    #pragma unroll
    for (int kt = 0; kt < 2; kt++) {
        s8v b = *(const s8v*)&ACT[w][pq*ASTRIDE + kt*32 + G*8];
        s8v wfr = *(const s8v*)&WF[(4+kt)*512 + l*8];
        acc1 = __builtin_amdgcn_mfma_f32_16x16x32_bf16(wfr, b, acc1, 0, 0, 0);
    }
    float sig_raw = acc1[0];          // h1[0], valid at G==0

    // ---- build C0 activation: sh(0..15) | app(16..63) | geo(64..78) ----
    {
        float invn = 1.0f / sqrtf(dx*dx + dy*dy + dz*dz);
        float ndx = dx*invn, ndy = dy*invn, ndz = dz*invn;
        float xx = ndx*ndx, yy = ndy*ndy, zz = ndz*ndz;
        float xy = ndx*ndy, yz = ndy*ndz, xz = ndx*ndz;
        float s0, s1, s2, s3;
        if (G == 0) {
            s0 =  0.28209479177387814f;
            s1 = -0.48860251190291987f * ndy;
            s2 =  0.48860251190291987f * ndz;
            s3 = -0.48860251190291987f * ndx;
        } else if (G == 1) {
            s0 =  1.0925484305920792f * xy;
            s1 = -1.0925484305920792f * yz;
            s2 =  0.94617469575756f * zz - 0.31539156525252005f;
            s3 = -1.0925484305920792f * xz;
        } else if (G == 2) {
            s0 =  0.5462742152960396f * (xx - yy);
            s1 = -0.5900435899266435f * ndy * (3.f*xx - yy);
            s2 =  2.890611442640554f * xy * ndz;
            s3 = -0.4570457994644657f * ndy * (4.f*zz - xx - yy);
        } else {
            s0 =  0.37317633259011546f * ndz * (2.f*zz - 3.f*xx - 3.f*yy);
            s1 = -0.4570457994644657f * ndx * (4.f*zz - xx - yy);
            s2 =  1.445305721320277f * ndz * (xx - yy);
            s3 = -0.5900435899266435f * ndx * (xx - 3.f*yy);
        }
        *(u32*)&ACT[w][pq*ASTRIDE + 4*G]     = pack_bf(s0, s1);
        *(u32*)&ACT[w][pq*ASTRIDE + 4*G + 2] = pack_bf(s2, s3);
        // app rows
        *(u32*)&ACT[w][pq*ASTRIDE + 16 + 12*G     ] = pack_bf(a0[0], a0[1]);
        *(u32*)&ACT[w][pq*ASTRIDE + 16 + 12*G + 2 ] = pack_bf(a0[2], a0[3]);
        *(u32*)&ACT[w][pq*ASTRIDE + 16 + 12*G + 4 ] = pack_bf(a1[0], a1[1]);
        *(u32*)&ACT[w][pq*ASTRIDE + 16 + 12*G + 6 ] = pack_bf(a1[2], a1[3]);
        *(u32*)&ACT[w][pq*ASTRIDE + 16 + 12*G + 8 ] = pack_bf(a2[0], a2[1]);
        *(u32*)&ACT[w][pq*ASTRIDE + 16 + 12*G + 10] = pack_bf(a2[2], a2[3]);
        // geo rows: h1[1..15] -> feats 64..78 (raw acc1)
        #pragma unroll
        for (int r2 = 0; r2 < 4; r2++) {
            int fp = 4*G + r2;
            if (fp >= 1) ACT[w][pq*ASTRIDE + 63 + fp] = f2bf(acc1[r2]);
        }
    }

    // ---- C0: c1 = relu([sh,app,geo] @ W + cb0)  (M=64, K=96) ----
    f4v acc[4];
    #pragma unroll
    for (int mt = 0; mt < 4; mt++) acc[mt] = *(const f4v*)&BI[80 + mt*16 + 4*G];
    #pragma unroll
    for (int kt = 0; kt < 3; kt++) {
        s8v b = *(const s8v*)&ACT[w][pq*ASTRIDE + kt*32 + G*8];
        #pragma unroll
        for (int mt = 0; mt < 4; mt++) {
            s8v wfr = *(const s8v*)&WF[(6 + mt*3 + kt)*512 + l*8];
            acc[mt] = __builtin_amdgcn_mfma_f32_16x16x32_bf16(wfr, b, acc[mt], 0, 0, 0);
        }
    }
    #pragma unroll
    for (int mt = 0; mt < 4; mt++) {
        f4v v = acc[mt];
        *(u32*)&ACT[w][pq*ASTRIDE + mt*16 + 4*G]     = pack_bf(fmaxf(v[0],0.f), fmaxf(v[1],0.f));
        *(u32*)&ACT[w][pq*ASTRIDE + mt*16 + 4*G + 2] = pack_bf(fmaxf(v[2],0.f), fmaxf(v[3],0.f));
    }

    // ---- C1: c2 = relu(c1 @ cw1 + cb1)  (M=64, K=64) ----
    #pragma unroll
    for (int mt = 0; mt < 4; mt++) acc[mt] = *(const f4v*)&BI[144 + mt*16 + 4*G];
    #pragma unroll
    for (int kt = 0; kt < 2; kt++) {
        s8v b = *(const s8v*)&ACT[w][pq*ASTRIDE + kt*32 + G*8];
        #pragma unroll
        for (int mt = 0; mt < 4; mt++) {
            s8v wfr = *(const s8v*)&WF[(18 + mt*2 + kt)*512 + l*8];
            acc[mt] = __builtin_amdgcn_mfma_f32_16x16x32_bf16(wfr, b, acc[mt], 0, 0, 0);
        }
    }
    #pragma unroll
    for (int mt = 0; mt < 4; mt++) {
        f4v v = acc[mt];
        *(u32*)&ACT[w][pq*ASTRIDE + mt*16 + 4*G]     = pack_bf(fmaxf(v[0],0.f), fmaxf(v[1],0.f));
        *(u32*)&ACT[w][pq*ASTRIDE + mt*16 + 4*G + 2] = pack_bf(fmaxf(v[2],0.f), fmaxf(v[3],0.f));
    }

    // ---- C2: rgb = c2 @ cw2 + cb2  (M=16 padded, K=64) ----
    f4v acc2 = *(const f4v*)&BI[208 + 4*G];
    #pragma unroll
    for (int kt = 0; kt < 2; kt++) {
        s8v b = *(const s8v*)&ACT[w][pq*ASTRIDE + kt*32 + G*8];
        s8v wfr = *(const s8v*)&WF[(26+kt)*512 + l*8];
        acc2 = __builtin_amdgcn_mfma_f32_16x16x32_bf16(wfr, b, acc2, 0, 0, 0);
    }

    // ---- epilogue: lanes G==0 hold sigma(h1[0]) and rgb (feats 0..2) ----
    if (G == 0 && pl < P) {
        float z100 = 100.f * sig_raw;
        float sigma = (z100 > 20.f) ? sig_raw : (log1pf(expf(z100)) * 0.01f);
        f4v o4;
        o4[0] = sigma;
        o4[1] = 1.f/(1.f+expf(-acc2[0]));
        o4[2] = 1.f/(1.f+expf(-acc2[1]));
        o4[3] = 1.f/(1.f+expf(-acc2[2]));
        __builtin_nontemporal_store(o4, (f4v*)out + (size_t)(p0 + pl));
    }
}

// ======================= Fused fallback (ws too small) =====================
template <int USE_BF16>
__global__ __launch_bounds__(256) void nerf_fused(
    const float* __restrict__ x,
    const float* __restrict__ dvec,
    const int*   __restrict__ app_idx,
    const void*  __restrict__ tbl_raw,
    const float* __restrict__ app_table,
    const float* __restrict__ sw0, const float* __restrict__ sb0,
    const float* __restrict__ sw1, const float* __restrict__ sb1,
    const float* __restrict__ cw0, const float* __restrict__ cb0,
    const float* __restrict__ cw1, const float* __restrict__ cb1,
    const float* __restrict__ cw2, const float* __restrict__ cb2,
    float* __restrict__ out, Res16 rt, int n_pts)
{
    using CT = typename std::conditional<USE_BF16 != 0, unsigned, float2>::type;
    const CT* __restrict__ tbl = (const CT*)tbl_raw;

    int n = blockIdx.x * blockDim.x + threadIdx.x;
    if (n >= n_pts) return;

    float px = (x[3*n+0] + 1.f) * 0.5f;
    float py = (x[3*n+1] + 1.f) * 0.5f;
    float pz = (x[3*n+2] + 1.f) * 0.5f;

    float e[2*NL];
    #pragma unroll
    for (int l = 0; l < NL; l++) {
        float res = rt.r[l];
        float xs = px*res, ys = py*res, zs = pz*res;
        float fx = floorf(xs), fy = floorf(ys), fz = floorf(zs);
        float wx = xs - fx, wy = ys - fy, wz = zs - fz;
        float ax = 1.f - wx, ay = 1.f - wy, az = 1.f - wz;
        unsigned X = (unsigned)fx, Y = (unsigned)fy, Z = (unsigned)fz;
        unsigned hx0 = X,               hx1 = X + 1u;
        unsigned hy0 = Y * 2654435761u, hy1 = hy0 + 2654435761u;
        unsigned hz0 = Z * 805459861u,  hz1 = hz0 + 805459861u;
        const CT* base = tbl + (size_t)l * TBL_N;
        float e0 = 0.f, e1 = 0.f;
        #pragma unroll
        for (int c = 0; c < 8; c++) {
            unsigned idx = (((c & 4) ? hx1 : hx0) ^
                            ((c & 2) ? hy1 : hy0) ^
                            ((c & 1) ? hz1 : hz0)) & (TBL_N - 1u);
            CT v = base[idx];
            float f0, f1;
            corner_vals(v, f0, f1);
            float wgt = ((c & 4) ? wx : ax) * ((c & 2) ? wy : ay) * ((c & 1) ? wz : az);
            e0 += wgt * f0;
            e1 += wgt * f1;
        }
        e[2*l] = e0; e[2*l+1] = e1;
    }

    float h[HID];
    #pragma unroll
    for (int o = 0; o < HID; o++) h[o] = sb0[o];
    #pragma unroll
    for (int l = 0; l < NL; l++) {
        const float* r0 = sw0 + (2 * l) * HID;
        float e0 = e[2*l], e1 = e[2*l+1];
        #pragma unroll
        for (int o = 0; o < HID; o++) h[o] += e0 * r0[o] + e1 * r0[HID + o];
    }
    #pragma unroll
    for (int o = 0; o < HID; o++) h[o] = fmaxf(h[o], 0.f);

    float h1[16];
    #pragma unroll
    for (int o = 0; o < 16; o++) h1[o] = sb1[o];
    #pragma unroll
    for (int i = 0; i < HID; i++) {
        float v = h[i];
        const float* wr = sw1 + i * 16;
        #pragma unroll
        for (int o = 0; o < 16; o++) h1[o] += v * wr[o];
    }

    float z100 = 100.f * h1[0];
    float sigma = (z100 > 20.f) ? h1[0] : (log1pf(expf(z100)) * 0.01f);

    float dx = dvec[3*n+0], dy = dvec[3*n+1], dz = dvec[3*n+2];
    float invn = 1.0f / sqrtf(dx*dx + dy*dy + dz*dz);
    dx *= invn; dy *= invn; dz *= invn;
    float xx = dx*dx, yy = dy*dy, zz = dz*dz;
    float xy = dx*dy, yz = dy*dz, xz = dx*dz;
    float sh[16];
    sh[0]  = 0.28209479177387814f;
    sh[1]  = -0.48860251190291987f * dy;
    sh[2]  =  0.48860251190291987f * dz;
    sh[3]  = -0.48860251190291987f * dx;
    sh[4]  =  1.0925484305920792f * xy;
    sh[5]  = -1.0925484305920792f * yz;
    sh[6]  =  0.94617469575756f * zz - 0.31539156525252005f;
    sh[7]  = -1.0925484305920792f * xz;
    sh[8]  =  0.5462742152960396f * (xx - yy);
    sh[9]  = -0.5900435899266435f * dy * (3.f * xx - yy);
    sh[10] =  2.890611442640554f * xy * dz;
    sh[11] = -0.4570457994644657f * dy * (4.f * zz - xx - yy);
    sh[12] =  0.37317633259011546f * dz * (2.f * zz - 3.f * xx - 3.f * yy);
    sh[13] = -0.4570457994644657f * dx * (4.f * zz - xx - yy);
    sh[14] =  1.445305721320277f * dz * (xx - yy);
    sh[15] = -0.5900435899266435f * dx * (xx - 3.f * yy);

    float c1[HID];
    #pragma unroll
    for (int o = 0; o < HID; o++) c1[o] = cb0[o];
    #pragma unroll
    for (int i = 0; i < 15; i++) {
        float v = h1[i + 1];
        const float* wr = cw0 + i * HID;
        #pragma unroll
        for (int o = 0; o < HID; o++) c1[o] += v * wr[o];
    }
    #pragma unroll
    for (int i = 0; i < 16; i++) {
        float v = sh[i];
        const float* wr = cw0 + (15 + i) * HID;
        #pragma unroll
        for (int o = 0; o < HID; o++) c1[o] += v * wr[o];
    }
    {
        const float4* arow = reinterpret_cast<const float4*>(app_table + (size_t)app_idx[n] * 48);
        for (int j4 = 0; j4 < 12; j4++) {
            float4 v = arow[j4];
            const float* wr = cw0 + (31 + 4 * j4) * HID;
            #pragma unroll
            for (int o = 0; o < HID; o++) c1[o] += v.x * wr[o];
            #pragma unroll
            for (int o = 0; o < HID; o++) c1[o] += v.y * wr[HID + o];
            #pragma unroll
            for (int o = 0; o < HID; o++) c1[o] += v.z * wr[2 * HID + o];
            #pragma unroll
            for (int o = 0; o < HID; o++) c1[o] += v.w * wr[3 * HID + o];
        }
    }
    #pragma unroll
    for (int o = 0; o < HID; o++) c1[o] = fmaxf(c1[o], 0.f);

    float c2[HID];
    #pragma unroll
    for (int o = 0; o < HID; o++) c2[o] = cb1[o];
    #pragma unroll
    for (int i = 0; i < HID; i++) {
        float v = c1[i];
        const float* wr = cw1 + i * HID;
        #pragma unroll
        for (int o = 0; o < HID; o++) c2[o] += v * wr[o];
    }
    #pragma unroll
    for (int o = 0; o < HID; o++) c2[o] = fmaxf(c2[o], 0.f);

    float r = cb2[0], g = cb2[1], b = cb2[2];
    #pragma unroll
    for (int i = 0; i < HID; i++) {
        float v = c2[i];
        r += v * cw2[i * 3 + 0];
        g += v * cw2[i * 3 + 1];
        b += v * cw2[i * 3 + 2];
    }
    r = 1.f / (1.f + expf(-r));
    g = 1.f / (1.f + expf(-g));
    b = 1.f / (1.f + expf(-b));

    reinterpret_cast<float4*>(out)[n] = make_float4(sigma, r, g, b);
}

extern "C" void kernel_launch(void* const* d_in, const int* in_sizes, int n_in,
                              void* d_out, int out_size, void* d_ws, size_t ws_size,
                              hipStream_t stream) {
    const float* x         = (const float*)d_in[0];
    const float* dvec      = (const float*)d_in[1];
    const int*   app_idx   = (const int*)  d_in[2];
    const float* ht        = (const float*)d_in[3];
    const float* app_table = (const float*)d_in[4];
    const float* sw0 = (const float*)d_in[5];
    const float* sb0 = (const float*)d_in[6];
    const float* sw1 = (const float*)d_in[7];
    const float* sb1 = (const float*)d_in[8];
    const float* cw0 = (const float*)d_in[9];
    const float* cb0 = (const float*)d_in[10];
    const float* cw1 = (const float*)d_in[11];
    const float* cb1 = (const float*)d_in[12];
    const float* cw2 = (const float*)d_in[13];
    const float* cb2 = (const float*)d_in[14];

    int n_pts = in_sizes[0] / 3;

    Res16 rt;
    double bb = exp(log(2048.0 / 16.0) / 15.0);
    for (int l = 0; l < NL; l++) rt.r[l] = (float)floor(16.0 * pow(bb, (double)l));

    const size_t tbl_entries = (size_t)NL * TBL_N;
    const size_t tbl_bytes = tbl_entries * sizeof(unsigned);       // 32 MiB
    const size_t WFRAG_OFF = tbl_bytes;
    const size_t BIAS_OFF  = WFRAG_OFF + 14336 * 2;
    const size_t ENC_OFF   = (BIAS_OFF + 224 * 4 + 255) & ~(size_t)255;

    if (ws_size >= ENC_OFF + (4u << 20)) {
        int nent = (int)tbl_entries;
        hipLaunchKernelGGL(repack_bf16, dim3((nent + 255) / 256), dim3(256), 0, stream,
                           ht, (unsigned*)d_ws, nent);
        u16*   wfrag = (u16*)  ((char*)d_ws + WFRAG_OFF);
        float* biasb = (float*)((char*)d_ws + BIAS_OFF);
        hipLaunchKernelGGL(nerf_pack_w, dim3(1), dim3(256), 0, stream,
                           sw0, sb0, sw1, sb1, cw0, cb0, cw1, cb1, cw2, cb2,
                           wfrag, biasb);

        size_t cap = (ws_size - ENC_OFF) / 64;   // 64 B per point
        if (cap > (size_t)n_pts) cap = (size_t)n_pts;
        cap &= ~(size_t)255;
        if (cap == 0) cap = 256;
        u32* enc = (u32*)((char*)d_ws + ENC_OFF);

        for (long p0 = 0; p0 < (long)n_pts; p0 += (long)cap) {
            int P = (int)(((long)n_pts - p0) < (long)cap ? ((long)n_pts - p0) : (long)cap);
            hipLaunchKernelGGL(nerf_encode, dim3((P + 255) / 256), dim3(256), 0, stream,
                               x, (const unsigned*)d_ws, enc, rt, (int)p0, P, n_pts);
            hipLaunchKernelGGL(nerf_mlp_mfma, dim3((P + 63) / 64), dim3(256), 0, stream,
                               wfrag, biasb, (const u16*)enc,
                               dvec, app_idx, app_table,
                               (float*)d_out, (int)p0, P, n_pts);
        }
    } else if (ws_size >= tbl_bytes) {
        int nent = (int)tbl_entries;
        hipLaunchKernelGGL(repack_bf16, dim3((nent + 255) / 256), dim3(256), 0, stream,
                           ht, (unsigned*)d_ws, nent);
        dim3 g((n_pts + 255) / 256), blk(256);
        hipLaunchKernelGGL((nerf_fused<1>), g, blk, 0, stream,
                           x, dvec, app_idx, (const void*)d_ws, app_table,
                           sw0, sb0, sw1, sb1, cw0, cb0, cw1, cb1, cw2, cb2,
                           (float*)d_out, rt, n_pts);
    } else {
        dim3 g((n_pts + 255) / 256), blk(256);
        hipLaunchKernelGGL((nerf_fused<0>), g, blk, 0, stream,
                           x, dvec, app_idx, (const void*)ht, app_table,
                           sw0, sb0, sw1, sb1, cw0, cb0, cw1, cb1, cw2, cb2,
                           (float*)d_out, rt, n_pts);
    }
}

// Round 9
// 1285.494 us; speedup vs baseline: 15.0039x; 1.8144x over previous
//
#include <hip/hip_runtime.h>
#include <cmath>
#include <type_traits>

#define NL 16
#define TBL_N (1u << 19)
#define HID 64

typedef float f4v __attribute__((ext_vector_type(4)));
typedef float f2v __attribute__((ext_vector_type(2)));
typedef short s8v __attribute__((ext_vector_type(8)));
typedef unsigned int u32;
typedef unsigned short u16;

struct Res16 { float r[NL]; };

__device__ __host__ __forceinline__ unsigned short f2bf(float f) {
    unsigned u = __builtin_bit_cast(unsigned, f);
    unsigned r = (u + 0x7FFFu + ((u >> 16) & 1u)) >> 16;   // RNE
    return (unsigned short)r;
}
__device__ __forceinline__ u32 pack_bf(float a, float b) {
    return (u32)f2bf(a) | ((u32)f2bf(b) << 16);
}
__device__ __forceinline__ void corner_vals(unsigned v, float& f0, float& f1) {
    f0 = __uint_as_float(v << 16);
    f1 = __uint_as_float(v & 0xffff0000u);
}
__device__ __forceinline__ void corner_vals(float2 v, float& f0, float& f1) {
    f0 = v.x; f1 = v.y;
}

__global__ __launch_bounds__(256) void repack_bf16(const float* __restrict__ src,
                                                   unsigned* __restrict__ dst, int n) {
    int i = blockIdx.x * blockDim.x + threadIdx.x;
    if (i >= n) return;
    f2v v = __builtin_nontemporal_load((const f2v*)src + i);
    dst[i] = pack_bf(v.x, v.y);
}

// ======================= Kernel E: level-partitioned hash encode ===========
// blockIdx.y = level; dispatch walks x first, so the chip gathers from ~one
// 2 MB level at a time -> per-XCD L2-resident. enc stored l-major: enc[l*P+p].
__global__ __launch_bounds__(256) void nerf_encode(
    const float* __restrict__ x,
    const unsigned* __restrict__ tbl,
    u32* __restrict__ enc,
    Res16 rt, int p0, int P, int n_pts)
{
    int l = blockIdx.y;
    int tid = threadIdx.x;
    int p = blockIdx.x * 256 + tid;
    int pc = min(p, P - 1);
    int n = p0 + pc;

    float px = (__builtin_nontemporal_load(&x[3*n+0]) + 1.f) * 0.5f;
    float py = (__builtin_nontemporal_load(&x[3*n+1]) + 1.f) * 0.5f;
    float pz = (__builtin_nontemporal_load(&x[3*n+2]) + 1.f) * 0.5f;

    float res = rt.r[l];
    float xs = px*res, ys = py*res, zs = pz*res;
    float fx = floorf(xs), fy = floorf(ys), fz = floorf(zs);
    float wx = xs - fx, wy = ys - fy, wz = zs - fz;
    float ax = 1.f - wx, ay = 1.f - wy, az = 1.f - wz;
    unsigned X = (unsigned)fx, Y = (unsigned)fy, Z = (unsigned)fz;
    unsigned hx0 = X,               hx1 = X + 1u;
    unsigned hy0 = Y * 2654435761u, hy1 = hy0 + 2654435761u;
    unsigned hz0 = Z * 805459861u,  hz1 = hz0 + 805459861u;
    const unsigned* base = tbl + (size_t)l * TBL_N;

    float e0 = 0.f, e1 = 0.f;
    #pragma unroll
    for (int c = 0; c < 8; c++) {
        unsigned idx = (((c & 4) ? hx1 : hx0) ^
                        ((c & 2) ? hy1 : hy0) ^
                        ((c & 1) ? hz1 : hz0)) & (TBL_N - 1u);
        unsigned v = base[idx];
        float f0, f1;
        corner_vals(v, f0, f1);
        float wgt = ((c & 4) ? wx : ax) * ((c & 2) ? wy : ay) * ((c & 1) ? wz : az);
        e0 += wgt * f0;
        e1 += wgt * f1;
    }
    __builtin_nontemporal_store(pack_bf(e0, e1), &enc[(size_t)l * P + pc]);
}

// ======================= Pack weights into MFMA A-fragments ================
// Frag ids: L0: 0..3 (mt); L1: 4..5 (kt); C0: 6..17 (mt*3+kt);
//           C1: 18..25 (mt*2+kt); C2: 26..27 (kt).
// Frag element (lane,j) = W[featout = mt*16 + (lane&15)][featin = kt*32 + (lane>>4)*8 + j]
// C0 featin order permuted to [sh(0..15), app(16..63), geo(64..78), pad(79..95)].
__global__ __launch_bounds__(256) void nerf_pack_w(
    const float* __restrict__ sw0, const float* __restrict__ sb0,
    const float* __restrict__ sw1, const float* __restrict__ sb1,
    const float* __restrict__ cw0, const float* __restrict__ cb0,
    const float* __restrict__ cw1, const float* __restrict__ cb1,
    const float* __restrict__ cw2, const float* __restrict__ cb2,
    u16* __restrict__ wf, float* __restrict__ bi)
{
    int tid = threadIdx.x;
    for (int e = tid; e < 14336; e += 256) {
        int f = e >> 9, r = e & 511, lane = r >> 3, j = r & 7;
        int fo = lane & 15, G = lane >> 4;
        float val = 0.f;
        if (f < 4) {                       // L0: W = sw0^T, K=32
            int o = f*16 + fo, i = G*8 + j;
            val = sw0[i*64 + o];
        } else if (f < 6) {                // L1: K=64, M=16
            int o = fo, i = (f-4)*32 + G*8 + j;
            val = sw1[i*16 + o];
        } else if (f < 18) {               // C0: K=96 permuted
            int t = f - 6, mt = t / 3, kt = t % 3;
            int o = mt*16 + fo, i = kt*32 + G*8 + j;
            int row = (i < 16) ? (15 + i) : (i < 64) ? (31 + (i - 16)) : (i < 79) ? (i - 64) : -1;
            val = (row < 0) ? 0.f : cw0[row*64 + o];
        } else if (f < 26) {               // C1: K=64
            int t = f - 18, mt = t >> 1, kt = t & 1;
            int o = mt*16 + fo, i = kt*32 + G*8 + j;
            val = cw1[i*64 + o];
        } else {                           // C2: M=16 (3 real), K=64
            int kt = f - 26;
            int o = fo, i = kt*32 + G*8 + j;
            val = (o < 3) ? cw2[i*3 + o] : 0.f;
        }
        wf[e] = f2bf(val);
    }
    for (int i2 = tid; i2 < 224; i2 += 256) {
        float v;
        if (i2 < 64) v = sb0[i2];
        else if (i2 < 80) v = sb1[i2 - 64];
        else if (i2 < 144) v = cb0[i2 - 80];
        else if (i2 < 208) v = cb1[i2 - 144];
        else v = (i2 - 208 < 3) ? cb2[i2 - 208] : 0.f;
        bi[i2] = v;
    }
}

// ======================= Kernel M: MFMA MLP ================================
// 256 threads = 4 waves x 16 points. Activations always B-operand
// (col = lane&15 = point, k = feature, 8 contiguous per lane-group).
#define ASTRIDE 104   // ushorts per point row in ACT (>=96, 16B-multiple)

__global__ __launch_bounds__(256) void nerf_mlp_mfma(
    const u16* __restrict__ wfg, const float* __restrict__ big,
    const u32* __restrict__ enc,
    const float* __restrict__ dvec, const int* __restrict__ app_idx,
    const float* __restrict__ app_table,
    float* __restrict__ out, int p0, int P, int n_pts)
{
    __shared__ __align__(16) u16 WF[14336];
    __shared__ __align__(16) float BI[224];
    __shared__ __align__(16) u16 ACT[4][16 * ASTRIDE];

    int tid = threadIdx.x;
    int w = tid >> 6, l = tid & 63;
    int G = l >> 4, pq = l & 15;
    int pl = blockIdx.x * 64 + w * 16 + pq;
    int pc = min(pl, P - 1);
    int n = p0 + pc;

    // early streaming loads (overlap with staging).
    // enc is l-major: dword for level lv at enc[lv*P + p]; levels 4G..4G+3
    // give bf16 feats 8G..8G+7 in order.
    uint4 ed;
    {
        const u32* encp = enc + pc;
        ed.x = __builtin_nontemporal_load(encp + (size_t)(4*G+0) * P);
        ed.y = __builtin_nontemporal_load(encp + (size_t)(4*G+1) * P);
        ed.z = __builtin_nontemporal_load(encp + (size_t)(4*G+2) * P);
        ed.w = __builtin_nontemporal_load(encp + (size_t)(4*G+3) * P);
    }
    s8v encf = __builtin_bit_cast(s8v, ed);
    float dx = __builtin_nontemporal_load(&dvec[3*n+0]);
    float dy = __builtin_nontemporal_load(&dvec[3*n+1]);
    float dz = __builtin_nontemporal_load(&dvec[3*n+2]);
    int ai = app_idx[n];
    const f4v* arow = (const f4v*)(app_table + (size_t)ai * 48 + 12 * G);
    f4v a0 = arow[0], a1 = arow[1], a2 = arow[2];

    // stage fragments + biases
    for (int i = tid; i < 1792; i += 256) ((uint4*)WF)[i] = ((const uint4*)wfg)[i];
    for (int i = tid; i < 224; i += 256) BI[i] = big[i];
    // zero pad region (feats 79..95) once
    if (G == 3) {
        ACT[w][pq*ASTRIDE + 79] = 0;
        #pragma unroll
        for (int k = 0; k < 8; k++) *(u32*)&ACT[w][pq*ASTRIDE + 80 + 2*k] = 0u;
    }
    __syncthreads();

    // ---- L0: h = relu(enc @ sw0 + sb0)  (M=64 featout, K=32) ----
    f4v acc0[4];
    #pragma unroll
    for (int mt = 0; mt < 4; mt++) acc0[mt] = *(const f4v*)&BI[mt*16 + 4*G];
    #pragma unroll
    for (int mt = 0; mt < 4; mt++) {
        s8v wfr = *(const s8v*)&WF[mt*512 + l*8];
        acc0[mt] = __builtin_amdgcn_mfma_f32_16x16x32_bf16(wfr, encf, acc0[mt], 0, 0, 0);
    }
    #pragma unroll
    for (int mt = 0; mt < 4; mt++) {
        f4v v = acc0[mt];
        *(u32*)&ACT[w][pq*ASTRIDE + mt*16 + 4*G]     = pack_bf(fmaxf(v[0],0.f), fmaxf(v[1],0.f));
        *(u32*)&ACT[w][pq*ASTRIDE + mt*16 + 4*G + 2] = pack_bf(fmaxf(v[2],0.f), fmaxf(v[3],0.f));
    }

    // ---- L1: h1 = h @ sw1 + sb1 (M=16, K=64), raw (no relu) ----
    f4v acc1 = *(const f4v*)&BI[64 + 4*G];
    #pragma unroll
    for (int kt = 0; kt < 2; kt++) {
        s8v b = *(const s8v*)&ACT[w][pq*ASTRIDE + kt*32 + G*8];
        s8v wfr = *(const s8v*)&WF[(4+kt)*512 + l*8];
        acc1 = __builtin_amdgcn_mfma_f32_16x16x32_bf16(wfr, b, acc1, 0, 0, 0);
    }
    float sig_raw = acc1[0];          // h1[0], valid at G==0

    // ---- build C0 activation: sh(0..15) | app(16..63) | geo(64..78) ----
    {
        float invn = 1.0f / sqrtf(dx*dx + dy*dy + dz*dz);
        float ndx = dx*invn, ndy = dy*invn, ndz = dz*invn;
        float xx = ndx*ndx, yy = ndy*ndy, zz = ndz*ndz;
        float xy = ndx*ndy, yz = ndy*ndz, xz = ndx*ndz;
        float s0, s1, s2, s3;
        if (G == 0) {
            s0 =  0.28209479177387814f;
            s1 = -0.48860251190291987f * ndy;
            s2 =  0.48860251190291987f * ndz;
            s3 = -0.48860251190291987f * ndx;
        } else if (G == 1) {
            s0 =  1.0925484305920792f * xy;
            s1 = -1.0925484305920792f * yz;
            s2 =  0.94617469575756f * zz - 0.31539156525252005f;
            s3 = -1.0925484305920792f * xz;
        } else if (G == 2) {
            s0 =  0.5462742152960396f * (xx - yy);
            s1 = -0.5900435899266435f * ndy * (3.f*xx - yy);
            s2 =  2.890611442640554f * xy * ndz;
            s3 = -0.4570457994644657f * ndy * (4.f*zz - xx - yy);
        } else {
            s0 =  0.37317633259011546f * ndz * (2.f*zz - 3.f*xx - 3.f*yy);
            s1 = -0.4570457994644657f * ndx * (4.f*zz - xx - yy);
            s2 =  1.445305721320277f * ndz * (xx - yy);
            s3 = -0.5900435899266435f * ndx * (xx - 3.f*yy);
        }
        *(u32*)&ACT[w][pq*ASTRIDE + 4*G]     = pack_bf(s0, s1);
        *(u32*)&ACT[w][pq*ASTRIDE + 4*G + 2] = pack_bf(s2, s3);
        // app rows
        *(u32*)&ACT[w][pq*ASTRIDE + 16 + 12*G     ] = pack_bf(a0[0], a0[1]);
        *(u32*)&ACT[w][pq*ASTRIDE + 16 + 12*G + 2 ] = pack_bf(a0[2], a0[3]);
        *(u32*)&ACT[w][pq*ASTRIDE + 16 + 12*G + 4 ] = pack_bf(a1[0], a1[1]);
        *(u32*)&ACT[w][pq*ASTRIDE + 16 + 12*G + 6 ] = pack_bf(a1[2], a1[3]);
        *(u32*)&ACT[w][pq*ASTRIDE + 16 + 12*G + 8 ] = pack_bf(a2[0], a2[1]);
        *(u32*)&ACT[w][pq*ASTRIDE + 16 + 12*G + 10] = pack_bf(a2[2], a2[3]);
        // geo rows: h1[1..15] -> feats 64..78 (raw acc1)
        #pragma unroll
        for (int r2 = 0; r2 < 4; r2++) {
            int fp = 4*G + r2;
            if (fp >= 1) ACT[w][pq*ASTRIDE + 63 + fp] = f2bf(acc1[r2]);
        }
    }

    // ---- C0: c1 = relu([sh,app,geo] @ W + cb0)  (M=64, K=96) ----
    f4v acc[4];
    #pragma unroll
    for (int mt = 0; mt < 4; mt++) acc[mt] = *(const f4v*)&BI[80 + mt*16 + 4*G];
    #pragma unroll
    for (int kt = 0; kt < 3; kt++) {
        s8v b = *(const s8v*)&ACT[w][pq*ASTRIDE + kt*32 + G*8];
        #pragma unroll
        for (int mt = 0; mt < 4; mt++) {
            s8v wfr = *(const s8v*)&WF[(6 + mt*3 + kt)*512 + l*8];
            acc[mt] = __builtin_amdgcn_mfma_f32_16x16x32_bf16(wfr, b, acc[mt], 0, 0, 0);
        }
    }
    #pragma unroll
    for (int mt = 0; mt < 4; mt++) {
        f4v v = acc[mt];
        *(u32*)&ACT[w][pq*ASTRIDE + mt*16 + 4*G]     = pack_bf(fmaxf(v[0],0.f), fmaxf(v[1],0.f));
        *(u32*)&ACT[w][pq*ASTRIDE + mt*16 + 4*G + 2] = pack_bf(fmaxf(v[2],0.f), fmaxf(v[3],0.f));
    }

    // ---- C1: c2 = relu(c1 @ cw1 + cb1)  (M=64, K=64) ----
    #pragma unroll
    for (int mt = 0; mt < 4; mt++) acc[mt] = *(const f4v*)&BI[144 + mt*16 + 4*G];
    #pragma unroll
    for (int kt = 0; kt < 2; kt++) {
        s8v b = *(const s8v*)&ACT[w][pq*ASTRIDE + kt*32 + G*8];
        #pragma unroll
        for (int mt = 0; mt < 4; mt++) {
            s8v wfr = *(const s8v*)&WF[(18 + mt*2 + kt)*512 + l*8];
            acc[mt] = __builtin_amdgcn_mfma_f32_16x16x32_bf16(wfr, b, acc[mt], 0, 0, 0);
        }
    }
    #pragma unroll
    for (int mt = 0; mt < 4; mt++) {
        f4v v = acc[mt];
        *(u32*)&ACT[w][pq*ASTRIDE + mt*16 + 4*G]     = pack_bf(fmaxf(v[0],0.f), fmaxf(v[1],0.f));
        *(u32*)&ACT[w][pq*ASTRIDE + mt*16 + 4*G + 2] = pack_bf(fmaxf(v[2],0.f), fmaxf(v[3],0.f));
    }

    // ---- C2: rgb = c2 @ cw2 + cb2  (M=16 padded, K=64) ----
    f4v acc2 = *(const f4v*)&BI[208 + 4*G];
    #pragma unroll
    for (int kt = 0; kt < 2; kt++) {
        s8v b = *(const s8v*)&ACT[w][pq*ASTRIDE + kt*32 + G*8];
        s8v wfr = *(const s8v*)&WF[(26+kt)*512 + l*8];
        acc2 = __builtin_amdgcn_mfma_f32_16x16x32_bf16(wfr, b, acc2, 0, 0, 0);
    }

    // ---- epilogue: lanes G==0 hold sigma(h1[0]) and rgb (feats 0..2) ----
    if (G == 0 && pl < P) {
        float z100 = 100.f * sig_raw;
        float sigma = (z100 > 20.f) ? sig_raw : (log1pf(expf(z100)) * 0.01f);
        f4v o4;
        o4[0] = sigma;
        o4[1] = 1.f/(1.f+expf(-acc2[0]));
        o4[2] = 1.f/(1.f+expf(-acc2[1]));
        o4[3] = 1.f/(1.f+expf(-acc2[2]));
        __builtin_nontemporal_store(o4, (f4v*)out + (size_t)(p0 + pl));
    }
}

// ======================= Fused fallback (ws too small) =====================
template <int USE_BF16>
__global__ __launch_bounds__(256) void nerf_fused(
    const float* __restrict__ x,
    const float* __restrict__ dvec,
    const int*   __restrict__ app_idx,
    const void*  __restrict__ tbl_raw,
    const float* __restrict__ app_table,
    const float* __restrict__ sw0, const float* __restrict__ sb0,
    const float* __restrict__ sw1, const float* __restrict__ sb1,
    const float* __restrict__ cw0, const float* __restrict__ cb0,
    const float* __restrict__ cw1, const float* __restrict__ cb1,
    const float* __restrict__ cw2, const float* __restrict__ cb2,
    float* __restrict__ out, Res16 rt, int n_pts)
{
    using CT = typename std::conditional<USE_BF16 != 0, unsigned, float2>::type;
    const CT* __restrict__ tbl = (const CT*)tbl_raw;

    int n = blockIdx.x * blockDim.x + threadIdx.x;
    if (n >= n_pts) return;

    float px = (x[3*n+0] + 1.f) * 0.5f;
    float py = (x[3*n+1] + 1.f) * 0.5f;
    float pz = (x[3*n+2] + 1.f) * 0.5f;

    float e[2*NL];
    #pragma unroll
    for (int l = 0; l < NL; l++) {
        float res = rt.r[l];
        float xs = px*res, ys = py*res, zs = pz*res;
        float fx = floorf(xs), fy = floorf(ys), fz = floorf(zs);
        float wx = xs - fx, wy = ys - fy, wz = zs - fz;
        float ax = 1.f - wx, ay = 1.f - wy, az = 1.f - wz;
        unsigned X = (unsigned)fx, Y = (unsigned)fy, Z = (unsigned)fz;
        unsigned hx0 = X,               hx1 = X + 1u;
        unsigned hy0 = Y * 2654435761u, hy1 = hy0 + 2654435761u;
        unsigned hz0 = Z * 805459861u,  hz1 = hz0 + 805459861u;
        const CT* base = tbl + (size_t)l * TBL_N;
        float e0 = 0.f, e1 = 0.f;
        #pragma unroll
        for (int c = 0; c < 8; c++) {
            unsigned idx = (((c & 4) ? hx1 : hx0) ^
                            ((c & 2) ? hy1 : hy0) ^
                            ((c & 1) ? hz1 : hz0)) & (TBL_N - 1u);
            CT v = base[idx];
            float f0, f1;
            corner_vals(v, f0, f1);
            float wgt = ((c & 4) ? wx : ax) * ((c & 2) ? wy : ay) * ((c & 1) ? wz : az);
            e0 += wgt * f0;
            e1 += wgt * f1;
        }
        e[2*l] = e0; e[2*l+1] = e1;
    }

    float h[HID];
    #pragma unroll
    for (int o = 0; o < HID; o++) h[o] = sb0[o];
    #pragma unroll
    for (int l = 0; l < NL; l++) {
        const float* r0 = sw0 + (2 * l) * HID;
        float e0 = e[2*l], e1 = e[2*l+1];
        #pragma unroll
        for (int o = 0; o < HID; o++) h[o] += e0 * r0[o] + e1 * r0[HID + o];
    }
    #pragma unroll
    for (int o = 0; o < HID; o++) h[o] = fmaxf(h[o], 0.f);

    float h1[16];
    #pragma unroll
    for (int o = 0; o < 16; o++) h1[o] = sb1[o];
    #pragma unroll
    for (int i = 0; i < HID; i++) {
        float v = h[i];
        const float* wr = sw1 + i * 16;
        #pragma unroll
        for (int o = 0; o < 16; o++) h1[o] += v * wr[o];
    }

    float z100 = 100.f * h1[0];
    float sigma = (z100 > 20.f) ? h1[0] : (log1pf(expf(z100)) * 0.01f);

    float dx = dvec[3*n+0], dy = dvec[3*n+1], dz = dvec[3*n+2];
    float invn = 1.0f / sqrtf(dx*dx + dy*dy + dz*dz);
    dx *= invn; dy *= invn; dz *= invn;
    float xx = dx*dx, yy = dy*dy, zz = dz*dz;
    float xy = dx*dy, yz = dy*dz, xz = dx*dz;
    float sh[16];
    sh[0]  = 0.28209479177387814f;
    sh[1]  = -0.48860251190291987f * dy;
    sh[2]  =  0.48860251190291987f * dz;
    sh[3]  = -0.48860251190291987f * dx;
    sh[4]  =  1.0925484305920792f * xy;
    sh[5]  = -1.0925484305920792f * yz;
    sh[6]  =  0.94617469575756f * zz - 0.31539156525252005f;
    sh[7]  = -1.0925484305920792f * xz;
    sh[8]  =  0.5462742152960396f * (xx - yy);
    sh[9]  = -0.5900435899266435f * dy * (3.f * xx - yy);
    sh[10] =  2.890611442640554f * xy * dz;
    sh[11] = -0.4570457994644657f * dy * (4.f * zz - xx - yy);
    sh[12] =  0.37317633259011546f * dz * (2.f * zz - 3.f * xx - 3.f * yy);
    sh[13] = -0.4570457994644657f * dx * (4.f * zz - xx - yy);
    sh[14] =  1.445305721320277f * dz * (xx - yy);
    sh[15] = -0.5900435899266435f * dx * (xx - 3.f * yy);

    float c1[HID];
    #pragma unroll
    for (int o = 0; o < HID; o++) c1[o] = cb0[o];
    #pragma unroll
    for (int i = 0; i < 15; i++) {
        float v = h1[i + 1];
        const float* wr = cw0 + i * HID;
        #pragma unroll
        for (int o = 0; o < HID; o++) c1[o] += v * wr[o];
    }
    #pragma unroll
    for (int i = 0; i < 16; i++) {
        float v = sh[i];
        const float* wr = cw0 + (15 + i) * HID;
        #pragma unroll
        for (int o = 0; o < HID; o++) c1[o] += v * wr[o];
    }
    {
        const float4* arow = reinterpret_cast<const float4*>(app_table + (size_t)app_idx[n] * 48);
        for (int j4 = 0; j4 < 12; j4++) {
            float4 v = arow[j4];
            const float* wr = cw0 + (31 + 4 * j4) * HID;
            #pragma unroll
            for (int o = 0; o < HID; o++) c1[o] += v.x * wr[o];
            #pragma unroll
            for (int o = 0; o < HID; o++) c1[o] += v.y * wr[HID + o];
            #pragma unroll
            for (int o = 0; o < HID; o++) c1[o] += v.z * wr[2 * HID + o];
            #pragma unroll
            for (int o = 0; o < HID; o++) c1[o] += v.w * wr[3 * HID + o];
        }
    }
    #pragma unroll
    for (int o = 0; o < HID; o++) c1[o] = fmaxf(c1[o], 0.f);

    float c2[HID];
    #pragma unroll
    for (int o = 0; o < HID; o++) c2[o] = cb1[o];
    #pragma unroll
    for (int i = 0; i < HID; i++) {
        float v = c1[i];
        const float* wr = cw1 + i * HID;
        #pragma unroll
        for (int o = 0; o < HID; o++) c2[o] += v * wr[o];
    }
    #pragma unroll
    for (int o = 0; o < HID; o++) c2[o] = fmaxf(c2[o], 0.f);

    float r = cb2[0], g = cb2[1], b = cb2[2];
    #pragma unroll
    for (int i = 0; i < HID; i++) {
        float v = c2[i];
        r += v * cw2[i * 3 + 0];
        g += v * cw2[i * 3 + 1];
        b += v * cw2[i * 3 + 2];
    }
    r = 1.f / (1.f + expf(-r));
    g = 1.f / (1.f + expf(-g));
    b = 1.f / (1.f + expf(-b));

    reinterpret_cast<float4*>(out)[n] = make_float4(sigma, r, g, b);
}

extern "C" void kernel_launch(void* const* d_in, const int* in_sizes, int n_in,
                              void* d_out, int out_size, void* d_ws, size_t ws_size,
                              hipStream_t stream) {
    const float* x         = (const float*)d_in[0];
    const float* dvec      = (const float*)d_in[1];
    const int*   app_idx   = (const int*)  d_in[2];
    const float* ht        = (const float*)d_in[3];
    const float* app_table = (const float*)d_in[4];
    const float* sw0 = (const float*)d_in[5];
    const float* sb0 = (const float*)d_in[6];
    const float* sw1 = (const float*)d_in[7];
    const float* sb1 = (const float*)d_in[8];
    const float* cw0 = (const float*)d_in[9];
    const float* cb0 = (const float*)d_in[10];
    const float* cw1 = (const float*)d_in[11];
    const float* cb1 = (const float*)d_in[12];
    const float* cw2 = (const float*)d_in[13];
    const float* cb2 = (const float*)d_in[14];

    int n_pts = in_sizes[0] / 3;

    Res16 rt;
    double bb = exp(log(2048.0 / 16.0) / 15.0);
    for (int l = 0; l < NL; l++) rt.r[l] = (float)floor(16.0 * pow(bb, (double)l));

    const size_t tbl_entries = (size_t)NL * TBL_N;
    const size_t tbl_bytes = tbl_entries * sizeof(unsigned);       // 32 MiB
    const size_t WFRAG_OFF = tbl_bytes;
    const size_t BIAS_OFF  = WFRAG_OFF + 14336 * 2;
    const size_t ENC_OFF   = (BIAS_OFF + 224 * 4 + 255) & ~(size_t)255;

    if (ws_size >= ENC_OFF + (4u << 20)) {
        int nent = (int)tbl_entries;
        hipLaunchKernelGGL(repack_bf16, dim3((nent + 255) / 256), dim3(256), 0, stream,
                           ht, (unsigned*)d_ws, nent);
        u16*   wfrag = (u16*)  ((char*)d_ws + WFRAG_OFF);
        float* biasb = (float*)((char*)d_ws + BIAS_OFF);
        hipLaunchKernelGGL(nerf_pack_w, dim3(1), dim3(256), 0, stream,
                           sw0, sb0, sw1, sb1, cw0, cb0, cw1, cb1, cw2, cb2,
                           wfrag, biasb);

        size_t cap = (ws_size - ENC_OFF) / 64;   // 64 B per point
        if (cap > (size_t)n_pts) cap = (size_t)n_pts;
        cap &= ~(size_t)255;
        if (cap == 0) cap = 256;
        u32* enc = (u32*)((char*)d_ws + ENC_OFF);

        for (long p0 = 0; p0 < (long)n_pts; p0 += (long)cap) {
            int P = (int)(((long)n_pts - p0) < (long)cap ? ((long)n_pts - p0) : (long)cap);
            hipLaunchKernelGGL(nerf_encode, dim3((P + 255) / 256, NL), dim3(256), 0, stream,
                               x, (const unsigned*)d_ws, enc, rt, (int)p0, P, n_pts);
            hipLaunchKernelGGL(nerf_mlp_mfma, dim3((P + 63) / 64), dim3(256), 0, stream,
                               wfrag, biasb, enc,
                               dvec, app_idx, app_table,
                               (float*)d_out, (int)p0, P, n_pts);
        }
    } else if (ws_size >= tbl_bytes) {
        int nent = (int)tbl_entries;
        hipLaunchKernelGGL(repack_bf16, dim3((nent + 255) / 256), dim3(256), 0, stream,
                           ht, (unsigned*)d_ws, nent);
        dim3 g((n_pts + 255) / 256), blk(256);
        hipLaunchKernelGGL((nerf_fused<1>), g, blk, 0, stream,
                           x, dvec, app_idx, (const void*)d_ws, app_table,
                           sw0, sb0, sw1, sb1, cw0, cb0, cw1, cb1, cw2, cb2,
                           (float*)d_out, rt, n_pts);
    } else {
        dim3 g((n_pts + 255) / 256), blk(256);
        hipLaunchKernelGGL((nerf_fused<0>), g, blk, 0, stream,
                           x, dvec, app_idx, (const void*)ht, app_table,
                           sw0, sb0, sw1, sb1, cw0, cb0, cw1, cb1, cw2, cb2,
                           (float*)d_out, rt, n_pts);
    }
}

// Round 11
// 1113.821 us; speedup vs baseline: 17.3164x; 1.1541x over previous
//
#include <hip/hip_runtime.h>
#include <cmath>
#include <type_traits>

#define NL 16
#define TBL_N (1u << 19)
#define HID 64
#define NDL 6   // dense (coarse) levels

typedef float f4v __attribute__((ext_vector_type(4)));
typedef float f2v __attribute__((ext_vector_type(2)));
typedef short s8v __attribute__((ext_vector_type(8)));
typedef unsigned int u32;
typedef unsigned short u16;

struct Res16 { float r[NL]; };
struct DenseP { int R[NDL]; int off[NDL]; int total; };

__device__ __host__ __forceinline__ unsigned short f2bf(float f) {
    unsigned u = __builtin_bit_cast(unsigned, f);
    unsigned r = (u + 0x7FFFu + ((u >> 16) & 1u)) >> 16;   // RNE
    return (unsigned short)r;
}
__device__ __forceinline__ u32 pack_bf(float a, float b) {
    return (u32)f2bf(a) | ((u32)f2bf(b) << 16);
}
__device__ __forceinline__ void corner_vals(unsigned v, float& f0, float& f1) {
    f0 = __uint_as_float(v << 16);
    f1 = __uint_as_float(v & 0xffff0000u);
}
__device__ __forceinline__ void corner_vals(float2 v, float& f0, float& f1) {
    f0 = v.x; f1 = v.y;
}

__global__ __launch_bounds__(256) void repack_bf16(const float* __restrict__ src,
                                                   unsigned* __restrict__ dst, int n) {
    int i = blockIdx.x * blockDim.x + threadIdx.x;
    if (i >= n) return;
    f2v v = __builtin_nontemporal_load((const f2v*)src + i);
    dst[i] = pack_bf(v.x, v.y);
}

// ======================= Build dense z-pair tables for levels 0..5 =========
// dense[cell(X,Y,Z)] = { tbl[hash(X,Y,Z)], tbl[hash(X,Y,Z+1)] }
__global__ __launch_bounds__(256) void build_dense(
    const u32* __restrict__ tbl, uint2* __restrict__ dense, DenseP dp)
{
    int e = blockIdx.x * 256 + threadIdx.x;
    if (e >= dp.total) return;
    int l = 0;
    #pragma unroll
    for (int i = 1; i < NDL; i++) if (e >= dp.off[i]) l = i;
    int cell = e - dp.off[l];
    int R = dp.R[l];
    int Z = cell % R; int t = cell / R; int Y = t % R; int X = t / R;
    u32 hy = (u32)Y * 2654435761u;
    u32 hz0 = (u32)Z * 805459861u;
    u32 hz1 = hz0 + 805459861u;
    u32 i0 = ((u32)X ^ hy ^ hz0) & (TBL_N - 1u);
    u32 i1 = ((u32)X ^ hy ^ hz1) & (TBL_N - 1u);
    const u32* base = tbl + (size_t)l * TBL_N;
    dense[e] = make_uint2(base[i0], base[i1]);
}

// ======================= Kernel E: level-partitioned hash encode ===========
// blockIdx.y = level. Levels < NDL read the dense z-pair tables (4x 8B
// aligned loads, z-local); levels >= NDL use the hash path. enc is l-major.
__global__ __launch_bounds__(256) void nerf_encode(
    const float* __restrict__ x,
    const unsigned* __restrict__ tbl,
    const uint2* __restrict__ dense,
    u32* __restrict__ enc,
    Res16 rt, DenseP dp, int p0, int P, int n_pts)
{
    int l = blockIdx.y;
    int tid = threadIdx.x;
    int p = blockIdx.x * 256 + tid;
    int pc = min(p, P - 1);
    int n = p0 + pc;

    float px = (__builtin_nontemporal_load(&x[3*n+0]) + 1.f) * 0.5f;
    float py = (__builtin_nontemporal_load(&x[3*n+1]) + 1.f) * 0.5f;
    float pz = (__builtin_nontemporal_load(&x[3*n+2]) + 1.f) * 0.5f;

    float res = rt.r[l];
    float xs = px*res, ys = py*res, zs = pz*res;
    float fx = floorf(xs), fy = floorf(ys), fz = floorf(zs);
    float wx = xs - fx, wy = ys - fy, wz = zs - fz;
    float ax = 1.f - wx, ay = 1.f - wy, az = 1.f - wz;

    float e0 = 0.f, e1 = 0.f;
    if (l < NDL) {
        // ---- dense path ----
        int R = dp.R[l];
        int X = (int)fx, Y = (int)fy, Z = (int)fz;
        const uint2* dl = dense + dp.off[l];
        int c00 = (X * R + Y) * R + Z;
        uint2 v00 = dl[c00];
        uint2 v01 = dl[c00 + R];
        uint2 v10 = dl[c00 + R * R];
        uint2 v11 = dl[c00 + R * R + R];
        float wxy00 = ax*ay, wxy01 = ax*wy, wxy10 = wx*ay, wxy11 = wx*wy;
        float f0, f1;
        corner_vals(v00.x, f0, f1); e0 += wxy00*az*f0; e1 += wxy00*az*f1;
        corner_vals(v00.y, f0, f1); e0 += wxy00*wz*f0; e1 += wxy00*wz*f1;
        corner_vals(v01.x, f0, f1); e0 += wxy01*az*f0; e1 += wxy01*az*f1;
        corner_vals(v01.y, f0, f1); e0 += wxy01*wz*f0; e1 += wxy01*wz*f1;
        corner_vals(v10.x, f0, f1); e0 += wxy10*az*f0; e1 += wxy10*az*f1;
        corner_vals(v10.y, f0, f1); e0 += wxy10*wz*f0; e1 += wxy10*wz*f1;
        corner_vals(v11.x, f0, f1); e0 += wxy11*az*f0; e1 += wxy11*az*f1;
        corner_vals(v11.y, f0, f1); e0 += wxy11*wz*f0; e1 += wxy11*wz*f1;
    } else {
        // ---- hash path ----
        unsigned X = (unsigned)fx, Y = (unsigned)fy, Z = (unsigned)fz;
        unsigned hx0 = X,               hx1 = X + 1u;
        unsigned hy0 = Y * 2654435761u, hy1 = hy0 + 2654435761u;
        unsigned hz0 = Z * 805459861u,  hz1 = hz0 + 805459861u;
        const unsigned* base = tbl + (size_t)l * TBL_N;
        #pragma unroll
        for (int c = 0; c < 8; c++) {
            unsigned idx = (((c & 4) ? hx1 : hx0) ^
                            ((c & 2) ? hy1 : hy0) ^
                            ((c & 1) ? hz1 : hz0)) & (TBL_N - 1u);
            unsigned v = base[idx];
            float f0, f1;
            corner_vals(v, f0, f1);
            float wgt = ((c & 4) ? wx : ax) * ((c & 2) ? wy : ay) * ((c & 1) ? wz : az);
            e0 += wgt * f0;
            e1 += wgt * f1;
        }
    }
    __builtin_nontemporal_store(pack_bf(e0, e1), &enc[(size_t)l * P + pc]);
}

// ======================= Pack weights into MFMA A-fragments ================
__global__ __launch_bounds__(256) void nerf_pack_w(
    const float* __restrict__ sw0, const float* __restrict__ sb0,
    const float* __restrict__ sw1, const float* __restrict__ sb1,
    const float* __restrict__ cw0, const float* __restrict__ cb0,
    const float* __restrict__ cw1, const float* __restrict__ cb1,
    const float* __restrict__ cw2, const float* __restrict__ cb2,
    u16* __restrict__ wf, float* __restrict__ bi)
{
    int tid = threadIdx.x;
    for (int e = tid; e < 14336; e += 256) {
        int f = e >> 9, r = e & 511, lane = r >> 3, j = r & 7;
        int fo = lane & 15, G = lane >> 4;
        float val = 0.f;
        if (f < 4) {                       // L0: W = sw0^T, K=32
            int o = f*16 + fo, i = G*8 + j;
            val = sw0[i*64 + o];
        } else if (f < 6) {                // L1: K=64, M=16
            int o = fo, i = (f-4)*32 + G*8 + j;
            val = sw1[i*16 + o];
        } else if (f < 18) {               // C0: K=96 permuted
            int t = f - 6, mt = t / 3, kt = t % 3;
            int o = mt*16 + fo, i = kt*32 + G*8 + j;
            int row = (i < 16) ? (15 + i) : (i < 64) ? (31 + (i - 16)) : (i < 79) ? (i - 64) : -1;
            val = (row < 0) ? 0.f : cw0[row*64 + o];
        } else if (f < 26) {               // C1: K=64
            int t = f - 18, mt = t >> 1, kt = t & 1;
            int o = mt*16 + fo, i = kt*32 + G*8 + j;
            val = cw1[i*64 + o];
        } else {                           // C2: M=16 (3 real), K=64
            int kt = f - 26;
            int o = fo, i = kt*32 + G*8 + j;
            val = (o < 3) ? cw2[i*3 + o] : 0.f;
        }
        wf[e] = f2bf(val);
    }
    for (int i2 = tid; i2 < 224; i2 += 256) {
        float v;
        if (i2 < 64) v = sb0[i2];
        else if (i2 < 80) v = sb1[i2 - 64];
        else if (i2 < 144) v = cb0[i2 - 80];
        else if (i2 < 208) v = cb1[i2 - 144];
        else v = (i2 - 208 < 3) ? cb2[i2 - 208] : 0.f;
        bi[i2] = v;
    }
}

// ======================= Kernel M: MFMA MLP ================================
#define ASTRIDE 104   // ushorts per point row in ACT (>=96, 16B-multiple)

__global__ __launch_bounds__(256) void nerf_mlp_mfma(
    const u16* __restrict__ wfg, const float* __restrict__ big,
    const u32* __restrict__ enc,
    const float* __restrict__ dvec, const int* __restrict__ app_idx,
    const float* __restrict__ app_table,
    float* __restrict__ out, int p0, int P, int n_pts)
{
    __shared__ __align__(16) u16 WF[14336];
    __shared__ __align__(16) float BI[224];
    __shared__ __align__(16) u16 ACT[4][16 * ASTRIDE];

    int tid = threadIdx.x;
    int w = tid >> 6, l = tid & 63;
    int G = l >> 4, pq = l & 15;
    int pl = blockIdx.x * 64 + w * 16 + pq;
    int pc = min(pl, P - 1);
    int n = p0 + pc;

    uint4 ed;
    {
        const u32* encp = enc + pc;
        ed.x = __builtin_nontemporal_load(encp + (size_t)(4*G+0) * P);
        ed.y = __builtin_nontemporal_load(encp + (size_t)(4*G+1) * P);
        ed.z = __builtin_nontemporal_load(encp + (size_t)(4*G+2) * P);
        ed.w = __builtin_nontemporal_load(encp + (size_t)(4*G+3) * P);
    }
    s8v encf = __builtin_bit_cast(s8v, ed);
    float dx = __builtin_nontemporal_load(&dvec[3*n+0]);
    float dy = __builtin_nontemporal_load(&dvec[3*n+1]);
    float dz = __builtin_nontemporal_load(&dvec[3*n+2]);
    int ai = app_idx[n];
    const f4v* arow = (const f4v*)(app_table + (size_t)ai * 48 + 12 * G);
    f4v a0 = arow[0], a1 = arow[1], a2 = arow[2];

    for (int i = tid; i < 1792; i += 256) ((uint4*)WF)[i] = ((const uint4*)wfg)[i];
    for (int i = tid; i < 224; i += 256) BI[i] = big[i];
    if (G == 3) {
        ACT[w][pq*ASTRIDE + 79] = 0;
        #pragma unroll
        for (int k = 0; k < 8; k++) *(u32*)&ACT[w][pq*ASTRIDE + 80 + 2*k] = 0u;
    }
    __syncthreads();

    // ---- L0 ----
    f4v acc0[4];
    #pragma unroll
    for (int mt = 0; mt < 4; mt++) acc0[mt] = *(const f4v*)&BI[mt*16 + 4*G];
    #pragma unroll
    for (int mt = 0; mt < 4; mt++) {
        s8v wfr = *(const s8v*)&WF[mt*512 + l*8];
        acc0[mt] = __builtin_amdgcn_mfma_f32_16x16x32_bf16(wfr, encf, acc0[mt], 0, 0, 0);
    }
    #pragma unroll
    for (int mt = 0; mt < 4; mt++) {
        f4v v = acc0[mt];
        *(u32*)&ACT[w][pq*ASTRIDE + mt*16 + 4*G]     = pack_bf(fmaxf(v[0],0.f), fmaxf(v[1],0.f));
        *(u32*)&ACT[w][pq*ASTRIDE + mt*16 + 4*G + 2] = pack_bf(fmaxf(v[2],0.f), fmaxf(v[3],0.f));
    }

    // ---- L1 (raw) ----
    f4v acc1 = *(const f4v*)&BI[64 + 4*G];
    #pragma unroll
    for (int kt = 0; kt < 2; kt++) {
        s8v b = *(const s8v*)&ACT[w][pq*ASTRIDE + kt*32 + G*8];
        s8v wfr = *(const s8v*)&WF[(4+kt)*512 + l*8];
        acc1 = __builtin_amdgcn_mfma_f32_16x16x32_bf16(wfr, b, acc1, 0, 0, 0);
    }
    float sig_raw = acc1[0];

    // ---- C0 activation build ----
    {
        float invn = 1.0f / sqrtf(dx*dx + dy*dy + dz*dz);
        float ndx = dx*invn, ndy = dy*invn, ndz = dz*invn;
        float xx = ndx*ndx, yy = ndy*ndy, zz = ndz*ndz;
        float xy = ndx*ndy, yz = ndy*ndz, xz = ndx*ndz;
        float s0, s1, s2, s3;
        if (G == 0) {
            s0 =  0.28209479177387814f;
            s1 = -0.48860251190291987f * ndy;
            s2 =  0.48860251190291987f * ndz;
            s3 = -0.48860251190291987f * ndx;
        } else if (G == 1) {
            s0 =  1.0925484305920792f * xy;
            s1 = -1.0925484305920792f * yz;
            s2 =  0.94617469575756f * zz - 0.31539156525252005f;
            s3 = -1.0925484305920792f * xz;
        } else if (G == 2) {
            s0 =  0.5462742152960396f * (xx - yy);
            s1 = -0.5900435899266435f * ndy * (3.f*xx - yy);
            s2 =  2.890611442640554f * xy * ndz;
            s3 = -0.4570457994644657f * ndy * (4.f*zz - xx - yy);
        } else {
            s0 =  0.37317633259011546f * ndz * (2.f*zz - 3.f*xx - 3.f*yy);
            s1 = -0.4570457994644657f * ndx * (4.f*zz - xx - yy);
            s2 =  1.445305721320277f * ndz * (xx - yy);
            s3 = -0.5900435899266435f * ndx * (xx - 3.f*yy);
        }
        *(u32*)&ACT[w][pq*ASTRIDE + 4*G]     = pack_bf(s0, s1);
        *(u32*)&ACT[w][pq*ASTRIDE + 4*G + 2] = pack_bf(s2, s3);
        *(u32*)&ACT[w][pq*ASTRIDE + 16 + 12*G     ] = pack_bf(a0[0], a0[1]);
        *(u32*)&ACT[w][pq*ASTRIDE + 16 + 12*G + 2 ] = pack_bf(a0[2], a0[3]);
        *(u32*)&ACT[w][pq*ASTRIDE + 16 + 12*G + 4 ] = pack_bf(a1[0], a1[1]);
        *(u32*)&ACT[w][pq*ASTRIDE + 16 + 12*G + 6 ] = pack_bf(a1[2], a1[3]);
        *(u32*)&ACT[w][pq*ASTRIDE + 16 + 12*G + 8 ] = pack_bf(a2[0], a2[1]);
        *(u32*)&ACT[w][pq*ASTRIDE + 16 + 12*G + 10] = pack_bf(a2[2], a2[3]);
        #pragma unroll
        for (int r2 = 0; r2 < 4; r2++) {
            int fp = 4*G + r2;
            if (fp >= 1) ACT[w][pq*ASTRIDE + 63 + fp] = f2bf(acc1[r2]);
        }
    }

    // ---- C0 ----
    f4v acc[4];
    #pragma unroll
    for (int mt = 0; mt < 4; mt++) acc[mt] = *(const f4v*)&BI[80 + mt*16 + 4*G];
    #pragma unroll
    for (int kt = 0; kt < 3; kt++) {
        s8v b = *(const s8v*)&ACT[w][pq*ASTRIDE + kt*32 + G*8];
        #pragma unroll
        for (int mt = 0; mt < 4; mt++) {
            s8v wfr = *(const s8v*)&WF[(6 + mt*3 + kt)*512 + l*8];
            acc[mt] = __builtin_amdgcn_mfma_f32_16x16x32_bf16(wfr, b, acc[mt], 0, 0, 0);
        }
    }
    #pragma unroll
    for (int mt = 0; mt < 4; mt++) {
        f4v v = acc[mt];
        *(u32*)&ACT[w][pq*ASTRIDE + mt*16 + 4*G]     = pack_bf(fmaxf(v[0],0.f), fmaxf(v[1],0.f));
        *(u32*)&ACT[w][pq*ASTRIDE + mt*16 + 4*G + 2] = pack_bf(fmaxf(v[2],0.f), fmaxf(v[3],0.f));
    }

    // ---- C1 ----
    #pragma unroll
    for (int mt = 0; mt < 4; mt++) acc[mt] = *(const f4v*)&BI[144 + mt*16 + 4*G];
    #pragma unroll
    for (int kt = 0; kt < 2; kt++) {
        s8v b = *(const s8v*)&ACT[w][pq*ASTRIDE + kt*32 + G*8];
        #pragma unroll
        for (int mt = 0; mt < 4; mt++) {
            s8v wfr = *(const s8v*)&WF[(18 + mt*2 + kt)*512 + l*8];
            acc[mt] = __builtin_amdgcn_mfma_f32_16x16x32_bf16(wfr, b, acc[mt], 0, 0, 0);
        }
    }
    #pragma unroll
    for (int mt = 0; mt < 4; mt++) {
        f4v v = acc[mt];
        *(u32*)&ACT[w][pq*ASTRIDE + mt*16 + 4*G]     = pack_bf(fmaxf(v[0],0.f), fmaxf(v[1],0.f));
        *(u32*)&ACT[w][pq*ASTRIDE + mt*16 + 4*G + 2] = pack_bf(fmaxf(v[2],0.f), fmaxf(v[3],0.f));
    }

    // ---- C2 ----
    f4v acc2 = *(const f4v*)&BI[208 + 4*G];
    #pragma unroll
    for (int kt = 0; kt < 2; kt++) {
        s8v b = *(const s8v*)&ACT[w][pq*ASTRIDE + kt*32 + G*8];
        s8v wfr = *(const s8v*)&WF[(26+kt)*512 + l*8];
        acc2 = __builtin_amdgcn_mfma_f32_16x16x32_bf16(wfr, b, acc2, 0, 0, 0);
    }

    if (G == 0 && pl < P) {
        float z100 = 100.f * sig_raw;
        float sigma = (z100 > 20.f) ? sig_raw : (log1pf(expf(z100)) * 0.01f);
        f4v o4;
        o4[0] = sigma;
        o4[1] = 1.f/(1.f+expf(-acc2[0]));
        o4[2] = 1.f/(1.f+expf(-acc2[1]));
        o4[3] = 1.f/(1.f+expf(-acc2[2]));
        __builtin_nontemporal_store(o4, (f4v*)out + (size_t)(p0 + pl));
    }
}

// ======================= Fused fallback (ws too small) =====================
template <int USE_BF16>
__global__ __launch_bounds__(256) void nerf_fused(
    const float* __restrict__ x,
    const float* __restrict__ dvec,
    const int*   __restrict__ app_idx,
    const void*  __restrict__ tbl_raw,
    const float* __restrict__ app_table,
    const float* __restrict__ sw0, const float* __restrict__ sb0,
    const float* __restrict__ sw1, const float* __restrict__ sb1,
    const float* __restrict__ cw0, const float* __restrict__ cb0,
    const float* __restrict__ cw1, const float* __restrict__ cb1,
    const float* __restrict__ cw2, const float* __restrict__ cb2,
    float* __restrict__ out, Res16 rt, int n_pts)
{
    using CT = typename std::conditional<USE_BF16 != 0, unsigned, float2>::type;
    const CT* __restrict__ tbl = (const CT*)tbl_raw;

    int n = blockIdx.x * blockDim.x + threadIdx.x;
    if (n >= n_pts) return;

    float px = (x[3*n+0] + 1.f) * 0.5f;
    float py = (x[3*n+1] + 1.f) * 0.5f;
    float pz = (x[3*n+2] + 1.f) * 0.5f;

    float e[2*NL];
    #pragma unroll
    for (int l = 0; l < NL; l++) {
        float res = rt.r[l];
        float xs = px*res, ys = py*res, zs = pz*res;
        float fx = floorf(xs), fy = floorf(ys), fz = floorf(zs);
        float wx = xs - fx, wy = ys - fy, wz = zs - fz;
        float ax = 1.f - wx, ay = 1.f - wy, az = 1.f - wz;
        unsigned X = (unsigned)fx, Y = (unsigned)fy, Z = (unsigned)fz;
        unsigned hx0 = X,               hx1 = X + 1u;
        unsigned hy0 = Y * 2654435761u, hy1 = hy0 + 2654435761u;
        unsigned hz0 = Z * 805459861u,  hz1 = hz0 + 805459861u;
        const CT* base = tbl + (size_t)l * TBL_N;
        float e0 = 0.f, e1 = 0.f;
        #pragma unroll
        for (int c = 0; c < 8; c++) {
            unsigned idx = (((c & 4) ? hx1 : hx0) ^
                            ((c & 2) ? hy1 : hy0) ^
                            ((c & 1) ? hz1 : hz0)) & (TBL_N - 1u);
            CT v = base[idx];
            float f0, f1;
            corner_vals(v, f0, f1);
            float wgt = ((c & 4) ? wx : ax) * ((c & 2) ? wy : ay) * ((c & 1) ? wz : az);
            e0 += wgt * f0;
            e1 += wgt * f1;
        }
        e[2*l] = e0; e[2*l+1] = e1;
    }

    float h[HID];
    #pragma unroll
    for (int o = 0; o < HID; o++) h[o] = sb0[o];
    #pragma unroll
    for (int l = 0; l < NL; l++) {
        const float* r0 = sw0 + (2 * l) * HID;
        float e0 = e[2*l], e1 = e[2*l+1];
        #pragma unroll
        for (int o = 0; o < HID; o++) h[o] += e0 * r0[o] + e1 * r0[HID + o];
    }
    #pragma unroll
    for (int o = 0; o < HID; o++) h[o] = fmaxf(h[o], 0.f);

    float h1[16];
    #pragma unroll
    for (int o = 0; o < 16; o++) h1[o] = sb1[o];
    #pragma unroll
    for (int i = 0; i < HID; i++) {
        float v = h[i];
        const float* wr = sw1 + i * 16;
        #pragma unroll
        for (int o = 0; o < 16; o++) h1[o] += v * wr[o];
    }

    float z100 = 100.f * h1[0];
    float sigma = (z100 > 20.f) ? h1[0] : (log1pf(expf(z100)) * 0.01f);

    float dx = dvec[3*n+0], dy = dvec[3*n+1], dz = dvec[3*n+2];
    float invn = 1.0f / sqrtf(dx*dx + dy*dy + dz*dz);
    dx *= invn; dy *= invn; dz *= invn;
    float xx = dx*dx, yy = dy*dy, zz = dz*dz;
    float xy = dx*dy, yz = dy*dz, xz = dx*dz;
    float sh[16];
    sh[0]  = 0.28209479177387814f;
    sh[1]  = -0.48860251190291987f * dy;
    sh[2]  =  0.48860251190291987f * dz;
    sh[3]  = -0.48860251190291987f * dx;
    sh[4]  =  1.0925484305920792f * xy;
    sh[5]  = -1.0925484305920792f * yz;
    sh[6]  =  0.94617469575756f * zz - 0.31539156525252005f;
    sh[7]  = -1.0925484305920792f * xz;
    sh[8]  =  0.5462742152960396f * (xx - yy);
    sh[9]  = -0.5900435899266435f * dy * (3.f * xx - yy);
    sh[10] =  2.890611442640554f * xy * dz;
    sh[11] = -0.4570457994644657f * dy * (4.f * zz - xx - yy);
    sh[12] =  0.37317633259011546f * dz * (2.f * zz - 3.f * xx - 3.f * yy);
    sh[13] = -0.4570457994644657f * dx * (4.f * zz - xx - yy);
    sh[14] =  1.445305721320277f * dz * (xx - yy);
    sh[15] = -0.5900435899266435f * dx * (xx - 3.f * yy);

    float c1[HID];
    #pragma unroll
    for (int o = 0; o < HID; o++) c1[o] = cb0[o];
    #pragma unroll
    for (int i = 0; i < 15; i++) {
        float v = h1[i + 1];
        const float* wr = cw0 + i * HID;
        #pragma unroll
        for (int o = 0; o < HID; o++) c1[o] += v * wr[o];
    }
    #pragma unroll
    for (int i = 0; i < 16; i++) {
        float v = sh[i];
        const float* wr = cw0 + (15 + i) * HID;
        #pragma unroll
        for (int o = 0; o < HID; o++) c1[o] += v * wr[o];
    }
    {
        const float4* arow = reinterpret_cast<const float4*>(app_table + (size_t)app_idx[n] * 48);
        for (int j4 = 0; j4 < 12; j4++) {
            float4 v = arow[j4];
            const float* wr = cw0 + (31 + 4 * j4) * HID;
            #pragma unroll
            for (int o = 0; o < HID; o++) c1[o] += v.x * wr[o];
            #pragma unroll
            for (int o = 0; o < HID; o++) c1[o] += v.y * wr[HID + o];
            #pragma unroll
            for (int o = 0; o < HID; o++) c1[o] += v.z * wr[2 * HID + o];
            #pragma unroll
            for (int o = 0; o < HID; o++) c1[o] += v.w * wr[3 * HID + o];
        }
    }
    #pragma unroll
    for (int o = 0; o < HID; o++) c1[o] = fmaxf(c1[o], 0.f);

    float c2[HID];
    #pragma unroll
    for (int o = 0; o < HID; o++) c2[o] = cb1[o];
    #pragma unroll
    for (int i = 0; i < HID; i++) {
        float v = c1[i];
        const float* wr = cw1 + i * HID;
        #pragma unroll
        for (int o = 0; o < HID; o++) c2[o] += v * wr[o];
    }
    #pragma unroll
    for (int o = 0; o < HID; o++) c2[o] = fmaxf(c2[o], 0.f);

    float r = cb2[0], g = cb2[1], b = cb2[2];
    #pragma unroll
    for (int i = 0; i < HID; i++) {
        float v = c2[i];
        r += v * cw2[i * 3 + 0];
        g += v * cw2[i * 3 + 1];
        b += v * cw2[i * 3 + 2];
    }
    r = 1.f / (1.f + expf(-r));
    g = 1.f / (1.f + expf(-g));
    b = 1.f / (1.f + expf(-b));

    reinterpret_cast<float4*>(out)[n] = make_float4(sigma, r, g, b);
}

extern "C" void kernel_launch(void* const* d_in, const int* in_sizes, int n_in,
                              void* d_out, int out_size, void* d_ws, size_t ws_size,
                              hipStream_t stream) {
    const float* x         = (const float*)d_in[0];
    const float* dvec      = (const float*)d_in[1];
    const int*   app_idx   = (const int*)  d_in[2];
    const float* ht        = (const float*)d_in[3];
    const float* app_table = (const float*)d_in[4];
    const float* sw0 = (const float*)d_in[5];
    const float* sb0 = (const float*)d_in[6];
    const float* sw1 = (const float*)d_in[7];
    const float* sb1 = (const float*)d_in[8];
    const float* cw0 = (const float*)d_in[9];
    const float* cb0 = (const float*)d_in[10];
    const float* cw1 = (const float*)d_in[11];
    const float* cb1 = (const float*)d_in[12];
    const float* cw2 = (const float*)d_in[13];
    const float* cb2 = (const float*)d_in[14];

    int n_pts = in_sizes[0] / 3;

    Res16 rt;
    double bb = exp(log(2048.0 / 16.0) / 15.0);
    for (int l = 0; l < NL; l++) rt.r[l] = (float)floor(16.0 * pow(bb, (double)l));

    DenseP dp;
    {
        int acc = 0;
        for (int l = 0; l < NDL; l++) {
            dp.R[l] = (int)rt.r[l] + 1;
            dp.off[l] = acc;
            acc += dp.R[l] * dp.R[l] * dp.R[l];
        }
        dp.total = acc;
    }

    const size_t tbl_entries = (size_t)NL * TBL_N;
    const size_t tbl_bytes = tbl_entries * sizeof(unsigned);       // 32 MiB
    const size_t WFRAG_OFF = tbl_bytes;
    const size_t BIAS_OFF  = WFRAG_OFF + 14336 * 2;
    const size_t DENSE_OFF = (BIAS_OFF + 224 * 4 + 255) & ~(size_t)255;
    const size_t ENC_OFF   = (DENSE_OFF + (size_t)dp.total * 8 + 255) & ~(size_t)255;

    if (ws_size >= ENC_OFF + (4u << 20)) {
        int nent = (int)tbl_entries;
        hipLaunchKernelGGL(repack_bf16, dim3((nent + 255) / 256), dim3(256), 0, stream,
                           ht, (unsigned*)d_ws, nent);
        u16*   wfrag = (u16*)  ((char*)d_ws + WFRAG_OFF);
        float* biasb = (float*)((char*)d_ws + BIAS_OFF);
        uint2* dense = (uint2*)((char*)d_ws + DENSE_OFF);
        hipLaunchKernelGGL(nerf_pack_w, dim3(1), dim3(256), 0, stream,
                           sw0, sb0, sw1, sb1, cw0, cb0, cw1, cb1, cw2, cb2,
                           wfrag, biasb);
        hipLaunchKernelGGL(build_dense, dim3((dp.total + 255) / 256), dim3(256), 0, stream,
                           (const u32*)d_ws, dense, dp);

        size_t cap = (ws_size - ENC_OFF) / 64;   // 64 B per point
        if (cap > (size_t)n_pts) cap = (size_t)n_pts;
        cap &= ~(size_t)255;
        if (cap == 0) cap = 256;
        u32* enc = (u32*)((char*)d_ws + ENC_OFF);

        for (long p0 = 0; p0 < (long)n_pts; p0 += (long)cap) {
            int P = (int)(((long)n_pts - p0) < (long)cap ? ((long)n_pts - p0) : (long)cap);
            hipLaunchKernelGGL(nerf_encode, dim3((P + 255) / 256, NL), dim3(256), 0, stream,
                               x, (const unsigned*)d_ws, dense, enc, rt, dp, (int)p0, P, n_pts);
            hipLaunchKernelGGL(nerf_mlp_mfma, dim3((P + 63) / 64), dim3(256), 0, stream,
                               wfrag, biasb, enc,
                               dvec, app_idx, app_table,
                               (float*)d_out, (int)p0, P, n_pts);
        }
    } else if (ws_size >= tbl_bytes) {
        int nent = (int)tbl_entries;
        hipLaunchKernelGGL(repack_bf16, dim3((nent + 255) / 256), dim3(256), 0, stream,
                           ht, (unsigned*)d_ws, nent);
        dim3 g((n_pts + 255) / 256), blk(256);
        hipLaunchKernelGGL((nerf_fused<1>), g, blk, 0, stream,
                           x, dvec, app_idx, (const void*)d_ws, app_table,
                           sw0, sb0, sw1, sb1, cw0, cb0, cw1, cb1, cw2, cb2,
                           (float*)d_out, rt, n_pts);
    } else {
        dim3 g((n_pts + 255) / 256), blk(256);
        hipLaunchKernelGGL((nerf_fused<0>), g, blk, 0, stream,
                           x, dvec, app_idx, (const void*)ht, app_table,
                           sw0, sb0, sw1, sb1, cw0, cb0, cw1, cb1, cw2, cb2,
                           (float*)d_out, rt, n_pts);
    }
}